// Round 4
// baseline (286.630 us; speedup 1.0000x reference)
//
#include <hip/hip_runtime.h>
#include <hip/hip_bf16.h>
#include <math.h>

#define BB   2
#define CC   256
#define HSZ  64
#define WSZ  64
#define NQQ  4096
#define NHH  8
#define NPP  8
#define DHH  32
#define FFND 256
#define MT   (BB*NQQ)   // 8192 rows

typedef __attribute__((ext_vector_type(8))) short s8v;
typedef __attribute__((ext_vector_type(4))) float f4v;

static __device__ __forceinline__ ushort f2bu(float f) {
    __hip_bfloat16 h = __float2bfloat16(f);
    return *reinterpret_cast<ushort*>(&h);
}

// ---------------- weight prep: transpose f32 [K][N] -> bf16 [N][K] (K=256 always) ----------
__global__ __launch_bounds__(256) void wprep_kernel(
        const float* __restrict__ val_w, const float* __restrict__ off_w,
        const float* __restrict__ aw_w,  const float* __restrict__ out_w,
        const float* __restrict__ f1_w,  const float* __restrict__ f2_w,
        const float* __restrict__ off_b, const float* __restrict__ aw_b,
        ushort* __restrict__ wval01, ushort* __restrict__ wvalS,
        ushort* __restrict__ woffaw, ushort* __restrict__ wout,
        ushort* __restrict__ wf1, ushort* __restrict__ wf2,
        float* __restrict__ bOA) {
    int bid = blockIdx.x;
    if (bid >= 304) {                           // bias concat for off/aw
        int layer = bid - 304;
        int t = threadIdx.x;
        if (t < 192)
            bOA[layer * 192 + t] = (t < 128) ? off_b[layer * 128 + t]
                                             : aw_b[layer * 64 + (t - 128)];
        return;
    }
    const float* src; ushort* dst; int srcStride;
    if (bid < 32) {                 // wval01: layers 0,1 stacked along N (512 rows)
        int nt = bid & 7, kt = bid >> 3;
        int layer = nt >> 2, nn = (nt & 3) * 64;
        src = val_w + (size_t)layer * 65536 + (size_t)kt * 64 * 256 + nn; srcStride = 256;
        dst = wval01 + (size_t)nt * 64 * 256 + kt * 64;
    } else if (bid < 64) {          // wvalS: layers 2,3
        int b = bid - 32; int layer = b >> 4; int kt = (b >> 2) & 3; int nt = b & 3;
        src = val_w + (size_t)(2 + layer) * 65536 + (size_t)kt * 64 * 256 + nt * 64; srcStride = 256;
        dst = wvalS + (size_t)layer * 65536 + (size_t)nt * 64 * 256 + kt * 64;
    } else if (bid < 112) {         // woffaw: [192][256] per layer (off rows 0..127, aw 128..191)
        int b = bid - 64; int layer = b / 12; int rem = b % 12; int kt = rem / 3; int nt = rem % 3;
        if (nt < 2) { src = off_w + (size_t)layer * 256 * 128 + (size_t)kt * 64 * 128 + nt * 64; srcStride = 128; }
        else        { src = aw_w  + (size_t)layer * 256 * 64  + (size_t)kt * 64 * 64;            srcStride = 64;  }
        dst = woffaw + (size_t)layer * 192 * 256 + (size_t)nt * 64 * 256 + kt * 64;
    } else {                        // wout / wf1 / wf2
        int b = bid - 112; int fam = b >> 6; int bb = b & 63;
        int layer = bb >> 4; int kt = (bb >> 2) & 3; int nt = bb & 3;
        const float* s0 = (fam == 0) ? out_w : ((fam == 1) ? f1_w : f2_w);
        ushort* d0      = (fam == 0) ? wout  : ((fam == 1) ? wf1  : wf2);
        src = s0 + (size_t)layer * 65536 + (size_t)kt * 64 * 256 + nt * 64; srcStride = 256;
        dst = d0 + (size_t)layer * 65536 + (size_t)nt * 64 * 256 + kt * 64;
    }
    __shared__ float tl[64][65];
    int t = threadIdx.x; int r = t >> 6, c = t & 63;
    #pragma unroll
    for (int rr = 0; rr < 64; rr += 4)
        tl[rr + r][c] = src[(size_t)(rr + r) * srcStride + c];
    __syncthreads();
    #pragma unroll
    for (int rr = 0; rr < 64; rr += 4)
        dst[(size_t)(rr + r) * 256 + c] = f2bu(tl[c][rr + r]);
}

// ---------------- fuse: softmax channel fusion + NCHW -> [B,HW,C], bf16 out --------------
__global__ __launch_bounds__(256) void fuse_kernel(const float* __restrict__ f0,
        const float* __restrict__ f1, const float* __restrict__ fl,
        ushort* __restrict__ fused) {
    int bid = blockIdx.x;
    int b = bid >> 8;
    int c0 = ((bid >> 6) & 3) * 64;
    int q0 = (bid & 63) * 64;
    __shared__ float tl[64][65];
    int t = threadIdx.x;
    int r = t >> 6, c = t & 63;
    #pragma unroll
    for (int rr = 0; rr < 64; rr += 4) {
        int ch = c0 + rr + r;
        float l0 = fl[ch], l1 = fl[CC + ch];
        float m = fmaxf(l0, l1);
        float e0 = __expf(l0 - m), e1 = __expf(l1 - m);
        float inv = 1.0f / (e0 + e1);
        size_t o = ((size_t)b * CC + ch) * NQQ + q0 + c;
        tl[rr + r][c] = (f0[o] * e0 + f1[o] * e1) * inv;
    }
    __syncthreads();
    #pragma unroll
    for (int rr = 0; rr < 64; rr += 4)
        fused[((size_t)(b * NQQ + q0 + rr + r)) * CC + c0 + c] = f2bu(tl[c][rr + r]);
}

// ---------------- sine positional embedding [NQ, C] f32 ----------------
__global__ void pos_kernel(float* __restrict__ pos) {
    int idx = blockIdx.x * 256 + threadIdx.x;
    int c = idx % CC;
    int q = idx / CC;
    int h = q / WSZ, w = q % WSZ;
    const float scale = 6.28318530717958647692f;
    float coord;
    int cf = c;
    if (c < 128) coord = (float)(h + 1) / (64.0f + 1e-6f) * scale;
    else { coord = (float)(w + 1) / (64.0f + 1e-6f) * scale; cf = c - 128; }
    int k = cf >> 1;
    // 10000^(-k/64) = exp2(-k * log2(10000)/64)
    float v = coord * exp2f(-0.20762050593046016f * (float)k);
    pos[idx] = (cf & 1) ? __cosf(v) : __sinf(v);
}

// ---------------- reference points: sigmoid(qe @ ref_w + ref_b), wave per row ------------
__global__ __launch_bounds__(256) void refpts_kernel(const float* __restrict__ qemb,
        const float* __restrict__ rw, const float* __restrict__ rb, float* __restrict__ refp) {
    int row = blockIdx.x * 4 + (threadIdx.x >> 6);
    int l = threadIdx.x & 63;
    float4 v = *(const float4*)(qemb + (size_t)row * 512 + l * 4);
    float a0 = v.x * rw[(l * 4 + 0) * 2] + v.y * rw[(l * 4 + 1) * 2]
             + v.z * rw[(l * 4 + 2) * 2] + v.w * rw[(l * 4 + 3) * 2];
    float a1 = v.x * rw[(l * 4 + 0) * 2 + 1] + v.y * rw[(l * 4 + 1) * 2 + 1]
             + v.z * rw[(l * 4 + 2) * 2 + 1] + v.w * rw[(l * 4 + 3) * 2 + 1];
    #pragma unroll
    for (int o = 32; o > 0; o >>= 1) { a0 += __shfl_xor(a0, o); a1 += __shfl_xor(a1, o); }
    if (l == 0) {
        refp[row * 2 + 0] = 1.0f / (1.0f + __expf(-(a0 + rb[0])));
        refp[row * 2 + 1] = 1.0f / (1.0f + __expf(-(a1 + rb[1])));
    }
}

// ---------------- tgt init: query_embed[:, C:] broadcast over B, float4 ------------------
__global__ void tgt_init_kernel(const float* __restrict__ qemb, float* __restrict__ tgt) {
    int idx = blockIdx.x * 256 + threadIdx.x;   // MT*C/4
    int c4 = idx & 63;
    int q = (idx >> 6) & (NQQ - 1);
    *(float4*)(tgt + (size_t)idx * 4) = *(const float4*)(qemb + (size_t)q * 512 + 256 + c4 * 4);
}

// ================= fused-A single-stage MFMA GEMM =================
// C[M=8192, N] = A[M,256] @ Bt[N,256]^T + bias
// MODE: 0 f32 store | 1 bf16 relu store | 2 f32 accumulate | 3 relu f32 accumulate | 4 bf16 store
// ASRC: 0 bf16 buffer | 1 f32 LN(g,b)[+extra qemb stride 512] | 2 f32 + pos (stride 256) | 3 f32 cast
template<int MODE, int ASRC>
__global__ __launch_bounds__(256) void mgemm(const ushort* __restrict__ Abf,
                                             const float* __restrict__ Af,
                                             const float* __restrict__ g,
                                             const float* __restrict__ bt,
                                             const float* __restrict__ extra,
                                             const ushort* __restrict__ Bt,
                                             const float* __restrict__ bias,
                                             float* __restrict__ Cf,
                                             ushort* __restrict__ Cb,
                                             int N) {
    constexpr int LDT = 264;                  // ushort; 528B row stride (16B-aligned, bank-spread)
    __shared__ ushort As[64 * LDT];
    __shared__ ushort Bs[64 * LDT];
    const int t = threadIdx.x;
    const int m0 = blockIdx.x * 64, n0 = blockIdx.y * 64;
    const int rg = t >> 3;                    // 0..31, 8 threads per row
    const int lj = t & 7;
    const int col0 = lj * 32;

    #pragma unroll
    for (int r2 = 0; r2 < 64; r2 += 32) {
        int row = rg + r2;
        // ---- B tile (always bf16 [N][256]) ----
        {
            const ushort* srcB = Bt + (size_t)(n0 + row) * 256 + col0;
            ushort* dstB = Bs + row * LDT + col0;
            #pragma unroll
            for (int j = 0; j < 4; j++)
                *(int4*)(dstB + j * 8) = *(const int4*)(srcB + j * 8);
        }
        // ---- A tile ----
        int m = m0 + row;
        int q = m & (NQQ - 1);
        ushort* dstA = As + row * LDT + col0;
        if (ASRC == 0) {
            const ushort* srcA = Abf + (size_t)m * 256 + col0;
            #pragma unroll
            for (int j = 0; j < 4; j++)
                *(int4*)(dstA + j * 8) = *(const int4*)(srcA + j * 8);
        } else {
            const float* srcA = Af + (size_t)m * 256 + col0;
            float fv[32];
            #pragma unroll
            for (int j = 0; j < 8; j++)
                *(float4*)&fv[j * 4] = *(const float4*)(srcA + j * 4);
            if (ASRC == 1) {
                float s = 0.0f;
                #pragma unroll
                for (int k = 0; k < 32; k++) s += fv[k];
                s += __shfl_xor(s, 1); s += __shfl_xor(s, 2); s += __shfl_xor(s, 4);
                float mean = s * (1.0f / CC);
                float s2 = 0.0f;
                #pragma unroll
                for (int k = 0; k < 32; k++) { float d = fv[k] - mean; s2 += d * d; }
                s2 += __shfl_xor(s2, 1); s2 += __shfl_xor(s2, 2); s2 += __shfl_xor(s2, 4);
                float rstd = rsqrtf(s2 * (1.0f / CC) + 1e-5f);
                #pragma unroll
                for (int j = 0; j < 8; j++) {
                    float4 gv = *(const float4*)(g + col0 + j * 4);
                    float4 bv = *(const float4*)(bt + col0 + j * 4);
                    fv[j * 4 + 0] = (fv[j * 4 + 0] - mean) * rstd * gv.x + bv.x;
                    fv[j * 4 + 1] = (fv[j * 4 + 1] - mean) * rstd * gv.y + bv.y;
                    fv[j * 4 + 2] = (fv[j * 4 + 2] - mean) * rstd * gv.z + bv.z;
                    fv[j * 4 + 3] = (fv[j * 4 + 3] - mean) * rstd * gv.w + bv.w;
                }
                if (extra) {
                    const float* ep = extra + (size_t)q * 512 + col0;
                    #pragma unroll
                    for (int j = 0; j < 8; j++) {
                        float4 av = *(const float4*)(ep + j * 4);
                        fv[j * 4 + 0] += av.x; fv[j * 4 + 1] += av.y;
                        fv[j * 4 + 2] += av.z; fv[j * 4 + 3] += av.w;
                    }
                }
            } else if (ASRC == 2) {
                const float* ep = extra + (size_t)q * 256 + col0;
                #pragma unroll
                for (int j = 0; j < 8; j++) {
                    float4 av = *(const float4*)(ep + j * 4);
                    fv[j * 4 + 0] += av.x; fv[j * 4 + 1] += av.y;
                    fv[j * 4 + 2] += av.z; fv[j * 4 + 3] += av.w;
                }
            }
            #pragma unroll
            for (int j = 0; j < 4; j++) {
                ushort tmp[8];
                #pragma unroll
                for (int k = 0; k < 8; k++) tmp[k] = f2bu(fv[j * 8 + k]);
                *(int4*)(dstA + j * 8) = *(const int4*)tmp;
            }
        }
    }
    __syncthreads();

    const int l = t & 63;
    const int w = t >> 6;
    const int wm = w >> 1, wn = w & 1;
    const int fr = l & 15;
    const int fk8 = (l >> 4) * 8;
    f4v acc[2][2] = {};
    #pragma unroll
    for (int kk = 0; kk < 256; kk += 32) {
        s8v a0 = *(const s8v*)(As + (wm * 32 + fr) * LDT + kk + fk8);
        s8v a1 = *(const s8v*)(As + (wm * 32 + 16 + fr) * LDT + kk + fk8);
        s8v b0 = *(const s8v*)(Bs + (wn * 32 + fr) * LDT + kk + fk8);
        s8v b1 = *(const s8v*)(Bs + (wn * 32 + 16 + fr) * LDT + kk + fk8);
        acc[0][0] = __builtin_amdgcn_mfma_f32_16x16x32_bf16(a0, b0, acc[0][0], 0, 0, 0);
        acc[0][1] = __builtin_amdgcn_mfma_f32_16x16x32_bf16(a0, b1, acc[0][1], 0, 0, 0);
        acc[1][0] = __builtin_amdgcn_mfma_f32_16x16x32_bf16(a1, b0, acc[1][0], 0, 0, 0);
        acc[1][1] = __builtin_amdgcn_mfma_f32_16x16x32_bf16(a1, b1, acc[1][1], 0, 0, 0);
    }
    const int rb = (l >> 4) * 4;
    #pragma unroll
    for (int i = 0; i < 2; i++)
        #pragma unroll
        for (int j = 0; j < 2; j++) {
            int gm = m0 + wm * 32 + i * 16 + rb;
            int gn = n0 + wn * 32 + j * 16 + fr;
            float bz = bias[gn];
            #pragma unroll
            for (int r = 0; r < 4; r++) {
                float v = acc[i][j][r] + bz;
                size_t off = (size_t)(gm + r) * N + gn;
                if (MODE == 0)      Cf[off] = v;
                else if (MODE == 1) Cb[off] = f2bu(fmaxf(v, 0.0f));
                else if (MODE == 2) Cf[off] += v;
                else if (MODE == 3) Cf[off] += fmaxf(v, 0.0f);
                else                Cb[off] = f2bu(v);
            }
        }
}

// ---------------- deformable sampling: softmax(NP) fused, bf16 value, 8ch/thread ---------
__global__ __launch_bounds__(256) void sample_kernel(const ushort* __restrict__ value, int vstride,
        const float* __restrict__ offaw, const float* __restrict__ refp,
        int isSelf, ushort* __restrict__ samp) {
    int idx = blockIdx.x * 256 + threadIdx.x;   // MT*NH*4 = 262144
    int d8 = idx & 3;
    int h  = (idx >> 2) & 7;
    int q  = (idx >> 5) & (NQQ - 1);
    int b  = idx >> 17;
    int row = b * NQQ + q;
    float rxs, rys;
    if (isSelf) { rxs = (float)(q & 63) * 64.0f + 32.0f; rys = (float)(q >> 6) * 64.0f + 32.0f; }
    else        { rxs = refp[q * 2] * 64.0f;             rys = refp[q * 2 + 1] * 64.0f; }
    const float* oa = offaw + (size_t)row * 192;
    float lg[8];
    #pragma unroll
    for (int p = 0; p < 8; p++) lg[p] = oa[128 + h * 8 + p];
    float mx = lg[0];
    #pragma unroll
    for (int p = 1; p < 8; p++) mx = fmaxf(mx, lg[p]);
    float wg[8], wsum = 0.0f;
    #pragma unroll
    for (int p = 0; p < 8; p++) { wg[p] = __expf(lg[p] - mx); wsum += wg[p]; }
    float inv = 1.0f / wsum;
    const float* offp = oa + h * 16;
    const ushort* vb = value + (size_t)b * NQQ * vstride + h * 32 + d8 * 8;
    float acc[8] = {};
    #pragma unroll
    for (int p = 0; p < 8; p++) {
        float px = rxs + offp[p * 2]     - 0.5f;
        float py = rys + offp[p * 2 + 1] - 0.5f;
        float x0f = floorf(px), y0f = floorf(py);
        float lx = px - x0f, ly = py - y0f;
        int x0 = (int)x0f, y0 = (int)y0f;
        float wgt = wg[p] * inv;
        float w00 = (1 - lx) * (1 - ly) * wgt, w10 = lx * (1 - ly) * wgt;
        float w01 = (1 - lx) * ly * wgt,       w11 = lx * ly * wgt;
        #pragma unroll
        for (int cn = 0; cn < 4; cn++) {
            int xi = x0 + (cn & 1), yi = y0 + (cn >> 1);
            float wc = (cn == 0) ? w00 : (cn == 1) ? w10 : (cn == 2) ? w01 : w11;
            if (xi >= 0 && xi < WSZ && yi >= 0 && yi < HSZ) {
                uint4 uv = *(const uint4*)(vb + (size_t)(yi * WSZ + xi) * vstride);
                uint ua[4] = {uv.x, uv.y, uv.z, uv.w};
                #pragma unroll
                for (int k = 0; k < 4; k++) {
                    uint lo = ua[k] << 16;
                    uint hi = ua[k] & 0xffff0000u;
                    acc[k * 2 + 0] += wc * *reinterpret_cast<float*>(&lo);
                    acc[k * 2 + 1] += wc * *reinterpret_cast<float*>(&hi);
                }
            }
        }
    }
    ushort pk[8];
    #pragma unroll
    for (int k = 0; k < 8; k++) pk[k] = f2bu(acc[k]);
    *(int4*)(samp + (size_t)row * CC + h * 32 + d8 * 8) = *(const int4*)pk;
}

extern "C" void kernel_launch(void* const* d_in, const int* in_sizes, int n_in,
                              void* d_out, int out_size, void* d_ws, size_t ws_size,
                              hipStream_t stream) {
    const float* feat0 = (const float*)d_in[0];
    const float* feat1 = (const float*)d_in[1];
    const float* qemb  = (const float*)d_in[2];
    const float* ref_w = (const float*)d_in[3];
    const float* ref_b = (const float*)d_in[4];
    const float* fl    = (const float*)d_in[5];
    const float* ln1_g = (const float*)d_in[6];
    const float* ln1_b = (const float*)d_in[7];
    const float* off_w = (const float*)d_in[8];
    const float* off_b = (const float*)d_in[9];
    const float* aw_w  = (const float*)d_in[10];
    const float* aw_b  = (const float*)d_in[11];
    const float* val_w = (const float*)d_in[12];
    const float* val_b = (const float*)d_in[13];
    const float* out_w = (const float*)d_in[14];
    const float* out_b = (const float*)d_in[15];
    const float* ln2_g = (const float*)d_in[16];
    const float* ln2_b = (const float*)d_in[17];
    const float* f1_w  = (const float*)d_in[18];
    const float* f1_b  = (const float*)d_in[19];
    const float* f2_w  = (const float*)d_in[20];
    const float* f2_b  = (const float*)d_in[21];

    float* tgt = (float*)d_out;                              // [B,NQ,C] f32
    float* ws = (float*)d_ws;
    float* pos     = ws;                                     // 1,048,576 f32
    float* refp    = pos + 1048576;                          // 8,192 f32
    float* offaw   = refp + 8192;                            // MT*192 f32
    float* bOA     = offaw + (size_t)MT * 192;               // 768 f32
    ushort* value01= (ushort*)(bOA + 768);                   // MT*512 ushort
    ushort* wval01 = value01 + (size_t)MT * 512;             // 131072
    ushort* wvalS  = wval01 + 131072;                        // 131072
    ushort* woffaw = wvalS + 131072;                         // 196608
    ushort* wout   = woffaw + 196608;                        // 262144
    ushort* wf1    = wout + 262144;                          // 262144
    ushort* wf2    = wf1 + 262144;                           // 262144
    ushort* samp_bf= wf2 + 262144;                           // MT*C
    ushort* hbuf_bf= samp_bf + (size_t)MT * CC;              // MT*C
    ushort* fused_bf = hbuf_bf + (size_t)MT * CC;            // MT*C

    wprep_kernel<<<308, 256, 0, stream>>>(val_w, off_w, aw_w, out_w, f1_w, f2_w,
                                          off_b, aw_b,
                                          wval01, wvalS, woffaw, wout, wf1, wf2, bOA);
    fuse_kernel<<<512, 256, 0, stream>>>(feat0, feat1, fl, fused_bf);
    pos_kernel<<<NQQ * CC / 256, 256, 0, stream>>>(pos);
    refpts_kernel<<<NQQ / 4, 256, 0, stream>>>(qemb, ref_w, ref_b, refp);
    tgt_init_kernel<<<MT * CC / 4 / 256, 256, 0, stream>>>(qemb, tgt);

    // both cross-layer value projections at once: [MT,512] bf16
    mgemm<4, 0><<<dim3(MT / 64, 8), 256, 0, stream>>>(
        fused_bf, nullptr, nullptr, nullptr, nullptr, wval01, val_b, nullptr, value01, 512);

    for (int i = 0; i < 2; i++) {       // cross layers
        // offaw = (LN(tgt;ln1) + qemb) @ Woffaw + bOA   (fused LN in A-stage)
        mgemm<0, 1><<<dim3(MT / 64, 3), 256, 0, stream>>>(
            nullptr, tgt, ln1_g + i * CC, ln1_b + i * CC, qemb,
            woffaw + (size_t)i * 192 * 256, bOA + i * 192, offaw, nullptr, 192);
        sample_kernel<<<MT * NHH * 4 / 256, 256, 0, stream>>>(
            value01 + i * 256, 512, offaw, refp, 0, samp_bf);
        mgemm<2, 0><<<dim3(MT / 64, 4), 256, 0, stream>>>(
            samp_bf, nullptr, nullptr, nullptr, nullptr,
            wout + (size_t)i * 65536, out_b + i * CC, tgt, nullptr, 256);
        mgemm<1, 1><<<dim3(MT / 64, 4), 256, 0, stream>>>(
            nullptr, tgt, ln2_g + i * CC, ln2_b + i * CC, nullptr,
            wf1 + (size_t)i * 65536, f1_b + i * FFND, nullptr, hbuf_bf, 256);
        mgemm<3, 0><<<dim3(MT / 64, 4), 256, 0, stream>>>(
            hbuf_bf, nullptr, nullptr, nullptr, nullptr,
            wf2 + (size_t)i * 65536, f2_b + i * CC, tgt, nullptr, 256);
    }
    for (int i = 2; i < 4; i++) {       // self layers
        // value = bf16(tgt) @ Wval + b, stored bf16
        mgemm<4, 3><<<dim3(MT / 64, 4), 256, 0, stream>>>(
            nullptr, tgt, nullptr, nullptr, nullptr,
            wvalS + (size_t)(i - 2) * 65536, val_b + i * CC, nullptr, value01, 256);
        // offaw = (tgt + pos) @ Woffaw + bOA
        mgemm<0, 2><<<dim3(MT / 64, 3), 256, 0, stream>>>(
            nullptr, tgt, nullptr, nullptr, pos,
            woffaw + (size_t)i * 192 * 256, bOA + i * 192, offaw, nullptr, 192);
        sample_kernel<<<MT * NHH * 4 / 256, 256, 0, stream>>>(
            value01, 256, offaw, refp, 1, samp_bf);
        mgemm<2, 0><<<dim3(MT / 64, 4), 256, 0, stream>>>(
            samp_bf, nullptr, nullptr, nullptr, nullptr,
            wout + (size_t)i * 65536, out_b + i * CC, tgt, nullptr, 256);
        mgemm<1, 1><<<dim3(MT / 64, 4), 256, 0, stream>>>(
            nullptr, tgt, ln2_g + i * CC, ln2_b + i * CC, nullptr,
            wf1 + (size_t)i * 65536, f1_b + i * FFND, nullptr, hbuf_bf, 256);
        mgemm<3, 0><<<dim3(MT / 64, 4), 256, 0, stream>>>(
            hbuf_bf, nullptr, nullptr, nullptr, nullptr,
            wf2 + (size_t)i * 65536, f2_b + i * CC, tgt, nullptr, 256);
    }
}

// Round 5
// 268.391 us; speedup vs baseline: 1.0680x; 1.0680x over previous
//
#include <hip/hip_runtime.h>
#include <hip/hip_bf16.h>
#include <math.h>

#define CC   256
#define HSZ  64
#define WSZ  64
#define NQQ  4096
#define NHH  8
#define FFND 256
#define MT   8192

typedef __attribute__((ext_vector_type(8))) short s8v;
typedef __attribute__((ext_vector_type(4))) float f4v;

static __device__ __forceinline__ ushort f2bu(float f) {
    __hip_bfloat16 h = __float2bfloat16(f);
    return *reinterpret_cast<ushort*>(&h);
}

// ---------------- weight prep: transpose f32 [K][N] -> bf16 [N][K] (K=256 always) ----------
__global__ __launch_bounds__(256) void wprep_kernel(
        const float* __restrict__ val_w, const float* __restrict__ off_w,
        const float* __restrict__ aw_w,  const float* __restrict__ out_w,
        const float* __restrict__ f1_w,  const float* __restrict__ f2_w,
        const float* __restrict__ off_b, const float* __restrict__ aw_b,
        ushort* __restrict__ wval01, ushort* __restrict__ wvalS,
        ushort* __restrict__ woffaw, ushort* __restrict__ wout,
        ushort* __restrict__ wf1, ushort* __restrict__ wf2,
        float* __restrict__ bOA) {
    int bid = blockIdx.x;
    if (bid >= 304) {                           // bias concat for off/aw
        int layer = bid - 304;
        int t = threadIdx.x;
        if (t < 192)
            bOA[layer * 192 + t] = (t < 128) ? off_b[layer * 128 + t]
                                             : aw_b[layer * 64 + (t - 128)];
        return;
    }
    const float* src; ushort* dst; int srcStride;
    if (bid < 32) {                 // wval01: layers 0,1 stacked along N (512 rows)
        int nt = bid & 7, kt = bid >> 3;
        int layer = nt >> 2, nn = (nt & 3) * 64;
        src = val_w + (size_t)layer * 65536 + (size_t)kt * 64 * 256 + nn; srcStride = 256;
        dst = wval01 + (size_t)nt * 64 * 256 + kt * 64;
    } else if (bid < 64) {          // wvalS: layers 2,3
        int b = bid - 32; int layer = b >> 4; int kt = (b >> 2) & 3; int nt = b & 3;
        src = val_w + (size_t)(2 + layer) * 65536 + (size_t)kt * 64 * 256 + nt * 64; srcStride = 256;
        dst = wvalS + (size_t)layer * 65536 + (size_t)nt * 64 * 256 + kt * 64;
    } else if (bid < 112) {         // woffaw: [192][256] per layer (off rows 0..127, aw 128..191)
        int b = bid - 64; int layer = b / 12; int rem = b % 12; int kt = rem / 3; int nt = rem % 3;
        if (nt < 2) { src = off_w + (size_t)layer * 256 * 128 + (size_t)kt * 64 * 128 + nt * 64; srcStride = 128; }
        else        { src = aw_w  + (size_t)layer * 256 * 64  + (size_t)kt * 64 * 64;            srcStride = 64;  }
        dst = woffaw + (size_t)layer * 192 * 256 + (size_t)nt * 64 * 256 + kt * 64;
    } else {                        // wout / wf1 / wf2
        int b = bid - 112; int fam = b >> 6; int bb = b & 63;
        int layer = bb >> 4; int kt = (bb >> 2) & 3; int nt = bb & 3;
        const float* s0 = (fam == 0) ? out_w : ((fam == 1) ? f1_w : f2_w);
        ushort* d0      = (fam == 0) ? wout  : ((fam == 1) ? wf1  : wf2);
        src = s0 + (size_t)layer * 65536 + (size_t)kt * 64 * 256 + nt * 64; srcStride = 256;
        dst = d0 + (size_t)layer * 65536 + (size_t)nt * 64 * 256 + kt * 64;
    }
    __shared__ float tl[64][65];
    int t = threadIdx.x; int r = t >> 6, c = t & 63;
    #pragma unroll
    for (int rr = 0; rr < 64; rr += 4)
        tl[rr + r][c] = src[(size_t)(rr + r) * srcStride + c];
    __syncthreads();
    #pragma unroll
    for (int rr = 0; rr < 64; rr += 4)
        dst[(size_t)(rr + r) * 256 + c] = f2bu(tl[c][rr + r]);
}

// ---------------- fuse: softmax channel fusion + NCHW -> [B,HW,C], bf16 out --------------
__global__ __launch_bounds__(256) void fuse_kernel(const float* __restrict__ f0,
        const float* __restrict__ f1, const float* __restrict__ fl,
        ushort* __restrict__ fused) {
    int bid = blockIdx.x;
    int b = bid >> 8;
    int c0 = ((bid >> 6) & 3) * 64;
    int q0 = (bid & 63) * 64;
    __shared__ float tl[64][65];
    int t = threadIdx.x;
    int r = t >> 6, c = t & 63;
    #pragma unroll
    for (int rr = 0; rr < 64; rr += 4) {
        int ch = c0 + rr + r;
        float l0 = fl[ch], l1 = fl[CC + ch];
        float m = fmaxf(l0, l1);
        float e0 = __expf(l0 - m), e1 = __expf(l1 - m);
        float inv = 1.0f / (e0 + e1);
        size_t o = ((size_t)b * CC + ch) * NQQ + q0 + c;
        tl[rr + r][c] = (f0[o] * e0 + f1[o] * e1) * inv;
    }
    __syncthreads();
    #pragma unroll
    for (int rr = 0; rr < 64; rr += 4)
        fused[((size_t)(b * NQQ + q0 + rr + r)) * CC + c0 + c] = f2bu(tl[c][rr + r]);
}

// ---------------- prolog: pos embed + ref points + tgt init, one kernel ------------------
__global__ __launch_bounds__(256) void prolog_kernel(const float* __restrict__ qemb,
        const float* __restrict__ rw, const float* __restrict__ rb,
        float* __restrict__ pos, float* __restrict__ refp, float* __restrict__ tgt) {
    int bid = blockIdx.x;
    if (bid < 2048) {                       // pos: NQ*128 sin/cos pairs
        int idx = bid * 256 + threadIdx.x;
        int q = idx >> 7, pp = idx & 127;
        int p = pp >> 6, u = pp & 63;
        float coordbase = (p == 0) ? (float)((q >> 6) + 1) : (float)((q & 63) + 1);
        float coord = coordbase * (6.28318530717958647692f / (64.0f + 1e-6f));
        float v = coord * exp2f(-0.20762050593046016f * (float)u);  // 10000^(-u/64)
        float2 sc = make_float2(__sinf(v), __cosf(v));
        *(float2*)(pos + (size_t)q * 256 + p * 128 + u * 2) = sc;
    } else if (bid < 3072) {                // refpts: wave per row
        int row = (bid - 2048) * 4 + (threadIdx.x >> 6);
        int l = threadIdx.x & 63;
        float4 v = *(const float4*)(qemb + (size_t)row * 512 + l * 4);
        float a0 = v.x * rw[(l * 4 + 0) * 2] + v.y * rw[(l * 4 + 1) * 2]
                 + v.z * rw[(l * 4 + 2) * 2] + v.w * rw[(l * 4 + 3) * 2];
        float a1 = v.x * rw[(l * 4 + 0) * 2 + 1] + v.y * rw[(l * 4 + 1) * 2 + 1]
                 + v.z * rw[(l * 4 + 2) * 2 + 1] + v.w * rw[(l * 4 + 3) * 2 + 1];
        #pragma unroll
        for (int o = 32; o > 0; o >>= 1) { a0 += __shfl_xor(a0, o); a1 += __shfl_xor(a1, o); }
        if (l == 0) {
            refp[row * 2 + 0] = 1.0f / (1.0f + __expf(-(a0 + rb[0])));
            refp[row * 2 + 1] = 1.0f / (1.0f + __expf(-(a1 + rb[1])));
        }
    } else {                                // tgt init: query_embed[:, C:]
        int idx = (bid - 3072) * 256 + threadIdx.x;   // MT*64 float4s
        int c4 = idx & 63;
        int q = (idx >> 6) & (NQQ - 1);
        *(float4*)(tgt + (size_t)idx * 4) = *(const float4*)(qemb + (size_t)q * 512 + 256 + c4 * 4);
    }
}

// ================= fused-A single-stage MFMA GEMM (A-only LDS, B direct global) ==========
// C[M=8192, N] = A[M,256] @ Bt[N,256]^T + bias
// MODE: 0 f32 store | 4 bf16 store
// ASRC: 0 bf16 buffer | 1 f32 LN(g,b)[+extra qemb stride 512]
template<int MODE, int ASRC>
__global__ __launch_bounds__(256) void mgemm(const ushort* __restrict__ Abf,
                                             const float* __restrict__ Af,
                                             const float* __restrict__ g,
                                             const float* __restrict__ bt,
                                             const float* __restrict__ extra,
                                             const ushort* __restrict__ Bt,
                                             const float* __restrict__ bias,
                                             float* __restrict__ Cf,
                                             ushort* __restrict__ Cb,
                                             int N) {
    constexpr int LDT = 264;
    __shared__ ushort As[64 * LDT];
    const int t = threadIdx.x;
    const int m0 = blockIdx.x * 64, n0 = blockIdx.y * 64;
    const int rg = t >> 3, lj = t & 7, col0 = lj * 32;

    #pragma unroll
    for (int r2 = 0; r2 < 64; r2 += 32) {
        int row = rg + r2;
        int m = m0 + row;
        int q = m & (NQQ - 1);
        ushort* dstA = As + row * LDT + col0;
        if (ASRC == 0) {
            const ushort* srcA = Abf + (size_t)m * 256 + col0;
            #pragma unroll
            for (int j = 0; j < 4; j++)
                *(int4*)(dstA + j * 8) = *(const int4*)(srcA + j * 8);
        } else {
            const float* srcA = Af + (size_t)m * 256 + col0;
            float fv[32];
            #pragma unroll
            for (int j = 0; j < 8; j++)
                *(float4*)&fv[j * 4] = *(const float4*)(srcA + j * 4);
            float s = 0.0f;
            #pragma unroll
            for (int k = 0; k < 32; k++) s += fv[k];
            s += __shfl_xor(s, 1); s += __shfl_xor(s, 2); s += __shfl_xor(s, 4);
            float mean = s * (1.0f / CC);
            float s2 = 0.0f;
            #pragma unroll
            for (int k = 0; k < 32; k++) { float d = fv[k] - mean; s2 += d * d; }
            s2 += __shfl_xor(s2, 1); s2 += __shfl_xor(s2, 2); s2 += __shfl_xor(s2, 4);
            float rstd = rsqrtf(s2 * (1.0f / CC) + 1e-5f);
            #pragma unroll
            for (int j = 0; j < 8; j++) {
                float4 gv = *(const float4*)(g + col0 + j * 4);
                float4 bv = *(const float4*)(bt + col0 + j * 4);
                fv[j * 4 + 0] = (fv[j * 4 + 0] - mean) * rstd * gv.x + bv.x;
                fv[j * 4 + 1] = (fv[j * 4 + 1] - mean) * rstd * gv.y + bv.y;
                fv[j * 4 + 2] = (fv[j * 4 + 2] - mean) * rstd * gv.z + bv.z;
                fv[j * 4 + 3] = (fv[j * 4 + 3] - mean) * rstd * gv.w + bv.w;
            }
            if (extra) {
                const float* ep = extra + (size_t)q * 512 + col0;
                #pragma unroll
                for (int j = 0; j < 8; j++) {
                    float4 av = *(const float4*)(ep + j * 4);
                    fv[j * 4 + 0] += av.x; fv[j * 4 + 1] += av.y;
                    fv[j * 4 + 2] += av.z; fv[j * 4 + 3] += av.w;
                }
            }
            #pragma unroll
            for (int j = 0; j < 4; j++) {
                ushort tmp[8];
                #pragma unroll
                for (int k = 0; k < 8; k++) tmp[k] = f2bu(fv[j * 8 + k]);
                *(int4*)(dstA + j * 8) = *(const int4*)tmp;
            }
        }
    }
    __syncthreads();

    const int l = t & 63;
    const int w = t >> 6;
    const int wm = w >> 1, wn = w & 1;
    const int fr = l & 15;
    const int fk8 = (l >> 4) * 8;
    const ushort* B0 = Bt + (size_t)(n0 + wn * 32 + fr) * 256 + fk8;
    const ushort* B1 = B0 + 16 * 256;
    f4v acc[2][2] = {};
    #pragma unroll
    for (int kk = 0; kk < 256; kk += 32) {
        s8v b0 = *(const s8v*)(B0 + kk);
        s8v b1 = *(const s8v*)(B1 + kk);
        s8v a0 = *(const s8v*)(As + (wm * 32 + fr) * LDT + kk + fk8);
        s8v a1 = *(const s8v*)(As + (wm * 32 + 16 + fr) * LDT + kk + fk8);
        acc[0][0] = __builtin_amdgcn_mfma_f32_16x16x32_bf16(a0, b0, acc[0][0], 0, 0, 0);
        acc[0][1] = __builtin_amdgcn_mfma_f32_16x16x32_bf16(a0, b1, acc[0][1], 0, 0, 0);
        acc[1][0] = __builtin_amdgcn_mfma_f32_16x16x32_bf16(a1, b0, acc[1][0], 0, 0, 0);
        acc[1][1] = __builtin_amdgcn_mfma_f32_16x16x32_bf16(a1, b1, acc[1][1], 0, 0, 0);
    }
    const int rb = (l >> 4) * 4;
    #pragma unroll
    for (int i = 0; i < 2; i++)
        #pragma unroll
        for (int j = 0; j < 2; j++) {
            int gm = m0 + wm * 32 + i * 16 + rb;
            int gn = n0 + wn * 32 + j * 16 + fr;
            float bz = bias[gn];
            #pragma unroll
            for (int r = 0; r < 4; r++) {
                float v = acc[i][j][r] + bz;
                size_t off = (size_t)(gm + r) * N + gn;
                if (MODE == 0) Cf[off] = v;
                else           Cb[off] = f2bu(v);
            }
        }
}

// ---------------- self-layer value || offaw fused GEMM ----------------
// blockIdx.y 0..3: value = bf16(tgt) @ wval + val_b  (bf16, stride 256)
// blockIdx.y 4..6: offaw = bf16(tgt+pos) @ woffaw + bOA (f32, stride 192)
__global__ __launch_bounds__(256) void valoffaw_gemm(const float* __restrict__ tgt,
        const float* __restrict__ pos, const ushort* __restrict__ wvalL,
        const ushort* __restrict__ woffawL, const float* __restrict__ val_bL,
        const float* __restrict__ bOAL, ushort* __restrict__ value,
        float* __restrict__ offaw) {
    constexpr int LDT = 264;
    __shared__ ushort As[64 * LDT];
    const int t = threadIdx.x;
    const bool isVal = blockIdx.y < 4;
    const int m0 = blockIdx.x * 64;
    const int n0 = (isVal ? blockIdx.y : (blockIdx.y - 4)) * 64;
    const ushort* Bt = isVal ? wvalL : woffawL;
    const int rg = t >> 3, lj = t & 7, col0 = lj * 32;

    #pragma unroll
    for (int r2 = 0; r2 < 64; r2 += 32) {
        int row = rg + r2;
        int m = m0 + row;
        int q = m & (NQQ - 1);
        const float* srcA = tgt + (size_t)m * 256 + col0;
        float fv[32];
        #pragma unroll
        for (int j = 0; j < 8; j++)
            *(float4*)&fv[j * 4] = *(const float4*)(srcA + j * 4);
        if (!isVal) {
            const float* ep = pos + (size_t)q * 256 + col0;
            #pragma unroll
            for (int j = 0; j < 8; j++) {
                float4 av = *(const float4*)(ep + j * 4);
                fv[j * 4 + 0] += av.x; fv[j * 4 + 1] += av.y;
                fv[j * 4 + 2] += av.z; fv[j * 4 + 3] += av.w;
            }
        }
        ushort* dstA = As + row * LDT + col0;
        #pragma unroll
        for (int j = 0; j < 4; j++) {
            ushort tmp[8];
            #pragma unroll
            for (int k = 0; k < 8; k++) tmp[k] = f2bu(fv[j * 8 + k]);
            *(int4*)(dstA + j * 8) = *(const int4*)tmp;
        }
    }
    __syncthreads();

    const int l = t & 63;
    const int w = t >> 6;
    const int wm = w >> 1, wn = w & 1;
    const int fr = l & 15;
    const int fk8 = (l >> 4) * 8;
    const ushort* B0 = Bt + (size_t)(n0 + wn * 32 + fr) * 256 + fk8;
    const ushort* B1 = B0 + 16 * 256;
    f4v acc[2][2] = {};
    #pragma unroll
    for (int kk = 0; kk < 256; kk += 32) {
        s8v b0 = *(const s8v*)(B0 + kk);
        s8v b1 = *(const s8v*)(B1 + kk);
        s8v a0 = *(const s8v*)(As + (wm * 32 + fr) * LDT + kk + fk8);
        s8v a1 = *(const s8v*)(As + (wm * 32 + 16 + fr) * LDT + kk + fk8);
        acc[0][0] = __builtin_amdgcn_mfma_f32_16x16x32_bf16(a0, b0, acc[0][0], 0, 0, 0);
        acc[0][1] = __builtin_amdgcn_mfma_f32_16x16x32_bf16(a0, b1, acc[0][1], 0, 0, 0);
        acc[1][0] = __builtin_amdgcn_mfma_f32_16x16x32_bf16(a1, b0, acc[1][0], 0, 0, 0);
        acc[1][1] = __builtin_amdgcn_mfma_f32_16x16x32_bf16(a1, b1, acc[1][1], 0, 0, 0);
    }
    const int rb = (l >> 4) * 4;
    #pragma unroll
    for (int i = 0; i < 2; i++)
        #pragma unroll
        for (int j = 0; j < 2; j++) {
            int gm = m0 + wm * 32 + i * 16 + rb;
            int gn = n0 + wn * 32 + j * 16 + fr;
            #pragma unroll
            for (int r = 0; r < 4; r++) {
                if (isVal) {
                    float v = acc[i][j][r] + val_bL[gn];
                    value[(size_t)(gm + r) * 256 + gn] = f2bu(v);
                } else {
                    float v = acc[i][j][r] + bOAL[gn];
                    offaw[(size_t)(gm + r) * 192 + gn] = v;
                }
            }
        }
}

// ---------------- tail: out-proj + residual + LN2 + FFN1 + FFN2 + residual ----------------
__device__ __forceinline__ void tail_gemm(const ushort* Abuf, const ushort* __restrict__ Bw,
                                          int w, int fr, int fk8, f4v (&acc)[4][4]) {
    #pragma unroll 4
    for (int kk = 0; kk < 256; kk += 32) {
        s8v a[4], b[4];
        #pragma unroll
        for (int i = 0; i < 4; i++)
            a[i] = *(const s8v*)(Abuf + (i * 16 + fr) * 264 + kk + fk8);
        #pragma unroll
        for (int j = 0; j < 4; j++)
            b[j] = *(const s8v*)(Bw + (size_t)(w * 64 + j * 16 + fr) * 256 + kk + fk8);
        #pragma unroll
        for (int i = 0; i < 4; i++)
            #pragma unroll
            for (int j = 0; j < 4; j++)
                acc[i][j] = __builtin_amdgcn_mfma_f32_16x16x32_bf16(a[i], b[j], acc[i][j], 0, 0, 0);
    }
}

__global__ __launch_bounds__(256) void tail_kernel(const ushort* __restrict__ samp,
        const ushort* __restrict__ woutL, const float* __restrict__ out_bL,
        const float* __restrict__ g2, const float* __restrict__ b2,
        const ushort* __restrict__ wf1L, const float* __restrict__ f1_bL,
        const ushort* __restrict__ wf2L, const float* __restrict__ f2_bL,
        float* __restrict__ tgt) {
    __shared__ ushort Abuf[64 * 264];
    __shared__ float pred[2][4][64];
    __shared__ float mrs[2][64];
    const int t = threadIdx.x, l = t & 63, w = t >> 6;
    const int fr = l & 15, fk8 = (l >> 4) * 8;
    const int rb = (l >> 4) * 4, cb = l & 15;
    const int m0 = blockIdx.x * 64;

    {   // stage samp tile
        const int rg = t >> 3, lj = t & 7, col0 = lj * 32;
        #pragma unroll
        for (int r2 = 0; r2 < 64; r2 += 32) {
            const ushort* src = samp + (size_t)(m0 + rg + r2) * 256 + col0;
            ushort* dst = Abuf + (rg + r2) * 264 + col0;
            #pragma unroll
            for (int j = 0; j < 4; j++)
                *(int4*)(dst + j * 8) = *(const int4*)(src + j * 8);
        }
    }
    __syncthreads();

    // phase 1: out-proj
    f4v acc[4][4] = {};
    tail_gemm(Abuf, woutL, w, fr, fk8, acc);
    __syncthreads();                 // done reading samp tile

    // residual add, write tgt, accumulate LN stats
    float ls[4][4] = {}, lq[4][4] = {};
    #pragma unroll
    for (int i = 0; i < 4; i++)
        #pragma unroll
        for (int j = 0; j < 4; j++) {
            int gcol = w * 64 + j * 16 + cb;
            float bz = out_bL[gcol];
            #pragma unroll
            for (int r = 0; r < 4; r++) {
                size_t off = (size_t)(m0 + i * 16 + rb + r) * 256 + gcol;
                float v = tgt[off] + acc[i][j][r] + bz;
                tgt[off] = v;
                ls[i][r] += v;
                lq[i][r] += v * v;
            }
        }
    #pragma unroll
    for (int o = 1; o < 16; o <<= 1)
        #pragma unroll
        for (int i = 0; i < 4; i++)
            #pragma unroll
            for (int r = 0; r < 4; r++) {
                ls[i][r] += __shfl_xor(ls[i][r], o);
                lq[i][r] += __shfl_xor(lq[i][r], o);
            }
    if (cb == 0)
        #pragma unroll
        for (int i = 0; i < 4; i++)
            #pragma unroll
            for (int r = 0; r < 4; r++) {
                pred[0][w][i * 16 + rb + r] = ls[i][r];
                pred[1][w][i * 16 + rb + r] = lq[i][r];
            }
    __syncthreads();
    if (t < 64) {
        float s = 0.0f, sq = 0.0f;
        #pragma unroll
        for (int ww = 0; ww < 4; ww++) { s += pred[0][ww][t]; sq += pred[1][ww][t]; }
        float mean = s * (1.0f / 256.0f);
        float var = sq * (1.0f / 256.0f) - mean * mean;
        mrs[0][t] = mean;
        mrs[1][t] = rsqrtf(var + 1e-5f);
    }
    __syncthreads();

    // LN -> Abuf bf16 (re-read tgt from L2)
    #pragma unroll
    for (int i = 0; i < 4; i++)
        #pragma unroll
        for (int r = 0; r < 4; r++) {
            int rloc = i * 16 + rb + r;
            float mean = mrs[0][rloc], rstd = mrs[1][rloc];
            #pragma unroll
            for (int j = 0; j < 4; j++) {
                int gcol = w * 64 + j * 16 + cb;
                float v = tgt[(size_t)(m0 + rloc) * 256 + gcol];
                Abuf[rloc * 264 + gcol] = f2bu((v - mean) * rstd * g2[gcol] + b2[gcol]);
            }
        }
    __syncthreads();

    // phase 2: FFN1 + relu
    f4v acc2[4][4] = {};
    tail_gemm(Abuf, wf1L, w, fr, fk8, acc2);
    __syncthreads();
    #pragma unroll
    for (int i = 0; i < 4; i++)
        #pragma unroll
        for (int j = 0; j < 4; j++) {
            int gcol = w * 64 + j * 16 + cb;
            float bz = f1_bL[gcol];
            #pragma unroll
            for (int r = 0; r < 4; r++)
                Abuf[(i * 16 + rb + r) * 264 + gcol] = f2bu(fmaxf(acc2[i][j][r] + bz, 0.0f));
        }
    __syncthreads();

    // phase 3: FFN2 + relu + residual
    f4v acc3[4][4] = {};
    tail_gemm(Abuf, wf2L, w, fr, fk8, acc3);
    #pragma unroll
    for (int i = 0; i < 4; i++)
        #pragma unroll
        for (int j = 0; j < 4; j++) {
            int gcol = w * 64 + j * 16 + cb;
            float bz = f2_bL[gcol];
            #pragma unroll
            for (int r = 0; r < 4; r++) {
                size_t off = (size_t)(m0 + i * 16 + rb + r) * 256 + gcol;
                tgt[off] += fmaxf(acc3[i][j][r] + bz, 0.0f);
            }
        }
}

// ---------------- deformable sampling: softmax(NP) fused, bf16 value, 8ch/thread ---------
__global__ __launch_bounds__(256) void sample_kernel(const ushort* __restrict__ value, int vstride,
        const float* __restrict__ offaw, const float* __restrict__ refp,
        int isSelf, ushort* __restrict__ samp) {
    int idx = blockIdx.x * 256 + threadIdx.x;   // MT*NH*4 = 262144
    int d8 = idx & 3;
    int h  = (idx >> 2) & 7;
    int q  = (idx >> 5) & (NQQ - 1);
    int b  = idx >> 17;
    int row = b * NQQ + q;
    float rxs, rys;
    if (isSelf) { rxs = (float)(q & 63) * 64.0f + 32.0f; rys = (float)(q >> 6) * 64.0f + 32.0f; }
    else        { rxs = refp[q * 2] * 64.0f;             rys = refp[q * 2 + 1] * 64.0f; }
    const float* oa = offaw + (size_t)row * 192;
    float lg[8];
    #pragma unroll
    for (int p = 0; p < 8; p++) lg[p] = oa[128 + h * 8 + p];
    float mx = lg[0];
    #pragma unroll
    for (int p = 1; p < 8; p++) mx = fmaxf(mx, lg[p]);
    float wg[8], wsum = 0.0f;
    #pragma unroll
    for (int p = 0; p < 8; p++) { wg[p] = __expf(lg[p] - mx); wsum += wg[p]; }
    float inv = 1.0f / wsum;
    const float* offp = oa + h * 16;
    const ushort* vb = value + (size_t)b * NQQ * vstride + h * 32 + d8 * 8;
    float acc[8] = {};
    #pragma unroll
    for (int p = 0; p < 8; p++) {
        float px = rxs + offp[p * 2]     - 0.5f;
        float py = rys + offp[p * 2 + 1] - 0.5f;
        float x0f = floorf(px), y0f = floorf(py);
        float lx = px - x0f, ly = py - y0f;
        int x0 = (int)x0f, y0 = (int)y0f;
        float wgt = wg[p] * inv;
        float w00 = (1 - lx) * (1 - ly) * wgt, w10 = lx * (1 - ly) * wgt;
        float w01 = (1 - lx) * ly * wgt,       w11 = lx * ly * wgt;
        #pragma unroll
        for (int cn = 0; cn < 4; cn++) {
            int xi = x0 + (cn & 1), yi = y0 + (cn >> 1);
            float wc = (cn == 0) ? w00 : (cn == 1) ? w10 : (cn == 2) ? w01 : w11;
            if (xi >= 0 && xi < WSZ && yi >= 0 && yi < HSZ) {
                uint4 uv = *(const uint4*)(vb + (size_t)(yi * WSZ + xi) * vstride);
                uint ua[4] = {uv.x, uv.y, uv.z, uv.w};
                #pragma unroll
                for (int k = 0; k < 4; k++) {
                    uint lo = ua[k] << 16;
                    uint hi = ua[k] & 0xffff0000u;
                    acc[k * 2 + 0] += wc * *reinterpret_cast<float*>(&lo);
                    acc[k * 2 + 1] += wc * *reinterpret_cast<float*>(&hi);
                }
            }
        }
    }
    ushort pk[8];
    #pragma unroll
    for (int k = 0; k < 8; k++) pk[k] = f2bu(acc[k]);
    *(int4*)(samp + (size_t)row * 256 + h * 32 + d8 * 8) = *(const int4*)pk;
}

extern "C" void kernel_launch(void* const* d_in, const int* in_sizes, int n_in,
                              void* d_out, int out_size, void* d_ws, size_t ws_size,
                              hipStream_t stream) {
    const float* feat0 = (const float*)d_in[0];
    const float* feat1 = (const float*)d_in[1];
    const float* qemb  = (const float*)d_in[2];
    const float* ref_w = (const float*)d_in[3];
    const float* ref_b = (const float*)d_in[4];
    const float* fl    = (const float*)d_in[5];
    const float* ln1_g = (const float*)d_in[6];
    const float* ln1_b = (const float*)d_in[7];
    const float* off_w = (const float*)d_in[8];
    const float* off_b = (const float*)d_in[9];
    const float* aw_w  = (const float*)d_in[10];
    const float* aw_b  = (const float*)d_in[11];
    const float* val_w = (const float*)d_in[12];
    const float* val_b = (const float*)d_in[13];
    const float* out_w = (const float*)d_in[14];
    const float* out_b = (const float*)d_in[15];
    const float* ln2_g = (const float*)d_in[16];
    const float* ln2_b = (const float*)d_in[17];
    const float* f1_w  = (const float*)d_in[18];
    const float* f1_b  = (const float*)d_in[19];
    const float* f2_w  = (const float*)d_in[20];
    const float* f2_b  = (const float*)d_in[21];

    float* tgt = (float*)d_out;                              // [B,NQ,C] f32
    float* ws = (float*)d_ws;
    float* pos     = ws;                                     // 1,048,576 f32
    float* refp    = pos + 1048576;                          // 8,192 f32
    float* offaw   = refp + 8192;                            // MT*192 f32
    float* bOA     = offaw + (size_t)MT * 192;               // 768 f32
    ushort* value01= (ushort*)(bOA + 768);                   // MT*512 ushort
    ushort* wval01 = value01 + (size_t)MT * 512;             // 131072
    ushort* wvalS  = wval01 + 131072;                        // 131072
    ushort* woffaw = wvalS + 131072;                         // 196608
    ushort* wout   = woffaw + 196608;                        // 262144
    ushort* wf1    = wout + 262144;                          // 262144
    ushort* wf2    = wf1 + 262144;                           // 262144
    ushort* samp_bf= wf2 + 262144;                           // MT*C
    ushort* fused_bf = samp_bf + (size_t)MT * CC;            // MT*C

    prolog_kernel<<<5120, 256, 0, stream>>>(qemb, ref_w, ref_b, pos, refp, tgt);
    wprep_kernel<<<308, 256, 0, stream>>>(val_w, off_w, aw_w, out_w, f1_w, f2_w,
                                          off_b, aw_b,
                                          wval01, wvalS, woffaw, wout, wf1, wf2, bOA);
    fuse_kernel<<<512, 256, 0, stream>>>(feat0, feat1, fl, fused_bf);

    // both cross-layer value projections at once: [MT,512] bf16
    mgemm<4, 0><<<dim3(128, 8), 256, 0, stream>>>(
        fused_bf, nullptr, nullptr, nullptr, nullptr, wval01, val_b, nullptr, value01, 512);

    for (int i = 0; i < 2; i++) {       // cross layers
        mgemm<0, 1><<<dim3(128, 3), 256, 0, stream>>>(
            nullptr, tgt, ln1_g + i * CC, ln1_b + i * CC, qemb,
            woffaw + (size_t)i * 49152, bOA + i * 192, offaw, nullptr, 192);
        sample_kernel<<<1024, 256, 0, stream>>>(
            value01 + i * 256, 512, offaw, refp, 0, samp_bf);
        tail_kernel<<<128, 256, 0, stream>>>(
            samp_bf, wout + (size_t)i * 65536, out_b + i * CC,
            ln2_g + i * CC, ln2_b + i * CC,
            wf1 + (size_t)i * 65536, f1_b + i * FFND,
            wf2 + (size_t)i * 65536, f2_b + i * CC, tgt);
    }
    for (int i = 2; i < 4; i++) {       // self layers
        valoffaw_gemm<<<dim3(128, 7), 256, 0, stream>>>(
            tgt, pos, wvalS + (size_t)(i - 2) * 65536, woffaw + (size_t)i * 49152,
            val_b + i * CC, bOA + i * 192, value01, offaw);
        sample_kernel<<<1024, 256, 0, stream>>>(
            value01, 256, offaw, refp, 1, samp_bf);
        tail_kernel<<<128, 256, 0, stream>>>(
            samp_bf, wout + (size_t)i * 65536, out_b + i * CC,
            ln2_g + i * CC, ln2_b + i * CC,
            wf1 + (size_t)i * 65536, f1_b + i * FFND,
            wf2 + (size_t)i * 65536, f2_b + i * CC, tgt);
    }
}

// Round 6
// 219.270 us; speedup vs baseline: 1.3072x; 1.2240x over previous
//
#include <hip/hip_runtime.h>
#include <hip/hip_bf16.h>
#include <math.h>

#define CC   256
#define NQQ  4096
#define MT   8192

typedef __attribute__((ext_vector_type(8))) short s8v;
typedef __attribute__((ext_vector_type(4))) float f4v;

static __device__ __forceinline__ ushort f2bu(float f) {
    __hip_bfloat16 h = __float2bfloat16(f);
    return *reinterpret_cast<ushort*>(&h);
}

// ======== setup: pos/refpts/tgt-init + weight transpose + fuse, one kernel ========
__global__ __launch_bounds__(256) void setup_kernel(
        const float* __restrict__ qemb, const float* __restrict__ rw,
        const float* __restrict__ rb,
        const float* __restrict__ feat0, const float* __restrict__ feat1,
        const float* __restrict__ fl,
        const float* __restrict__ val_w, const float* __restrict__ off_w,
        const float* __restrict__ aw_w,  const float* __restrict__ out_w,
        const float* __restrict__ f1_w,  const float* __restrict__ f2_w,
        const float* __restrict__ off_b, const float* __restrict__ aw_b,
        float* __restrict__ pos, float* __restrict__ refp, float* __restrict__ tgt,
        ushort* __restrict__ wval01, ushort* __restrict__ wvalS,
        ushort* __restrict__ woffaw, ushort* __restrict__ wout,
        ushort* __restrict__ wf1, ushort* __restrict__ wf2,
        float* __restrict__ bOA, ushort* __restrict__ fused) {
    __shared__ float tl[64][65];
    int bid = blockIdx.x;
    int t = threadIdx.x;
    if (bid < 2048) {                       // pos
        int idx = bid * 256 + t;
        int q = idx >> 7, pp = idx & 127;
        int p = pp >> 6, u = pp & 63;
        float coordbase = (p == 0) ? (float)((q >> 6) + 1) : (float)((q & 63) + 1);
        float coord = coordbase * (6.28318530717958647692f / (64.0f + 1e-6f));
        float v = coord * exp2f(-0.20762050593046016f * (float)u);
        *(float2*)(pos + (size_t)q * 256 + p * 128 + u * 2) = make_float2(__sinf(v), __cosf(v));
        return;
    }
    if (bid < 3072) {                       // refpts
        int row = (bid - 2048) * 4 + (t >> 6);
        int l = t & 63;
        float4 v = *(const float4*)(qemb + (size_t)row * 512 + l * 4);
        float a0 = v.x * rw[(l * 4 + 0) * 2] + v.y * rw[(l * 4 + 1) * 2]
                 + v.z * rw[(l * 4 + 2) * 2] + v.w * rw[(l * 4 + 3) * 2];
        float a1 = v.x * rw[(l * 4 + 0) * 2 + 1] + v.y * rw[(l * 4 + 1) * 2 + 1]
                 + v.z * rw[(l * 4 + 2) * 2 + 1] + v.w * rw[(l * 4 + 3) * 2 + 1];
        #pragma unroll
        for (int o = 32; o > 0; o >>= 1) { a0 += __shfl_xor(a0, o); a1 += __shfl_xor(a1, o); }
        if (l == 0) {
            refp[row * 2 + 0] = 1.0f / (1.0f + __expf(-(a0 + rb[0])));
            refp[row * 2 + 1] = 1.0f / (1.0f + __expf(-(a1 + rb[1])));
        }
        return;
    }
    if (bid < 5120) {                       // tgt init
        int idx = (bid - 3072) * 256 + t;
        int c4 = idx & 63;
        int q = (idx >> 6) & (NQQ - 1);
        *(float4*)(tgt + (size_t)idx * 4) = *(const float4*)(qemb + (size_t)q * 512 + 256 + c4 * 4);
        return;
    }
    if (bid < 5428) {                       // weight prep
        int wb = bid - 5120;
        if (wb >= 304) {
            int layer = wb - 304;
            if (t < 192)
                bOA[layer * 192 + t] = (t < 128) ? off_b[layer * 128 + t]
                                                 : aw_b[layer * 64 + (t - 128)];
            return;
        }
        const float* src; ushort* dst; int srcStride;
        if (wb < 32) {
            int nt = wb & 7, kt = wb >> 3;
            int layer = nt >> 2, nn = (nt & 3) * 64;
            src = val_w + (size_t)layer * 65536 + (size_t)kt * 64 * 256 + nn; srcStride = 256;
            dst = wval01 + (size_t)nt * 64 * 256 + kt * 64;
        } else if (wb < 64) {
            int b = wb - 32; int layer = b >> 4; int kt = (b >> 2) & 3; int nt = b & 3;
            src = val_w + (size_t)(2 + layer) * 65536 + (size_t)kt * 64 * 256 + nt * 64; srcStride = 256;
            dst = wvalS + (size_t)layer * 65536 + (size_t)nt * 64 * 256 + kt * 64;
        } else if (wb < 112) {
            int b = wb - 64; int layer = b / 12; int rem = b % 12; int kt = rem / 3; int nt = rem % 3;
            if (nt < 2) { src = off_w + (size_t)layer * 256 * 128 + (size_t)kt * 64 * 128 + nt * 64; srcStride = 128; }
            else        { src = aw_w  + (size_t)layer * 256 * 64  + (size_t)kt * 64 * 64;            srcStride = 64;  }
            dst = woffaw + (size_t)layer * 192 * 256 + (size_t)nt * 64 * 256 + kt * 64;
        } else {
            int b = wb - 112; int fam = b >> 6; int bb = b & 63;
            int layer = bb >> 4; int kt = (bb >> 2) & 3; int nt = bb & 3;
            const float* s0 = (fam == 0) ? out_w : ((fam == 1) ? f1_w : f2_w);
            ushort* d0      = (fam == 0) ? wout  : ((fam == 1) ? wf1  : wf2);
            src = s0 + (size_t)layer * 65536 + (size_t)kt * 64 * 256 + nt * 64; srcStride = 256;
            dst = d0 + (size_t)layer * 65536 + (size_t)nt * 64 * 256 + kt * 64;
        }
        int r = t >> 6, c = t & 63;
        #pragma unroll
        for (int rr = 0; rr < 64; rr += 4)
            tl[rr + r][c] = src[(size_t)(rr + r) * srcStride + c];
        __syncthreads();
        #pragma unroll
        for (int rr = 0; rr < 64; rr += 4)
            dst[(size_t)(rr + r) * 256 + c] = f2bu(tl[c][rr + r]);
        return;
    }
    {                                       // fuse
        int fb = bid - 5428;
        int b = fb >> 8;
        int c0 = ((fb >> 6) & 3) * 64;
        int q0 = (fb & 63) * 64;
        int r = t >> 6, c = t & 63;
        #pragma unroll
        for (int rr = 0; rr < 64; rr += 4) {
            int ch = c0 + rr + r;
            float l0 = fl[ch], l1 = fl[CC + ch];
            float m = fmaxf(l0, l1);
            float e0 = __expf(l0 - m), e1 = __expf(l1 - m);
            float inv = 1.0f / (e0 + e1);
            size_t o = ((size_t)b * CC + ch) * NQQ + q0 + c;
            tl[rr + r][c] = (feat0[o] * e0 + feat1[o] * e1) * inv;
        }
        __syncthreads();
        #pragma unroll
        for (int rr = 0; rr < 64; rr += 4)
            fused[((size_t)(b * NQQ + q0 + rr + r)) * CC + c0 + c] = f2bu(tl[c][rr + r]);
    }
}

// ======== projection GEMM: 16-row tiles, out bf16 = A @ Bt^T + bias ========
// ASRC 0: bf16 A; 1: f32 A (cast). col_base = blockIdx.y*256, out stride NS.
template<int ASRC>
__global__ __launch_bounds__(256) void pgemm(const ushort* __restrict__ Abf,
        const float* __restrict__ Af, const ushort* __restrict__ Bt,
        const float* __restrict__ bias, ushort* __restrict__ Cb, int NS) {
    __shared__ ushort Abuf[16 * 264];
    const int t = threadIdx.x;
    const int m0 = blockIdx.x * 16;
    const int cb0 = blockIdx.y * 256;
    {
        const int rg = t >> 4, lj = t & 15, c0 = lj * 16;
        ushort* dst = Abuf + rg * 264 + c0;
        if (ASRC == 0) {
            const ushort* src = Abf + (size_t)(m0 + rg) * 256 + c0;
            *(int4*)dst = *(const int4*)src;
            *(int4*)(dst + 8) = *(const int4*)(src + 8);
        } else {
            const float* src = Af + (size_t)(m0 + rg) * 256 + c0;
            ushort tmp[16];
            #pragma unroll
            for (int j = 0; j < 4; j++) {
                float4 v = *(const float4*)(src + j * 4);
                tmp[j * 4 + 0] = f2bu(v.x); tmp[j * 4 + 1] = f2bu(v.y);
                tmp[j * 4 + 2] = f2bu(v.z); tmp[j * 4 + 3] = f2bu(v.w);
            }
            *(int4*)dst = *(const int4*)tmp;
            *(int4*)(dst + 8) = *(const int4*)(tmp + 8);
        }
    }
    __syncthreads();
    const int l = t & 63, w = t >> 6;
    const int fr = l & 15, fk8 = (l >> 4) * 8, rb = (l >> 4) * 4;
    f4v acc[4] = {};
    #pragma unroll
    for (int kk = 0; kk < 256; kk += 32) {
        s8v a = *(const s8v*)(Abuf + fr * 264 + kk + fk8);
        #pragma unroll
        for (int j = 0; j < 4; j++) {
            s8v b = *(const s8v*)(Bt + (size_t)(cb0 + w * 64 + j * 16 + fr) * 256 + kk + fk8);
            acc[j] = __builtin_amdgcn_mfma_f32_16x16x32_bf16(a, b, acc[j], 0, 0, 0);
        }
    }
    #pragma unroll
    for (int j = 0; j < 4; j++) {
        int gcol = cb0 + w * 64 + j * 16 + fr;
        float bz = bias[gcol];
        #pragma unroll
        for (int r = 0; r < 4; r++)
            Cb[(size_t)(m0 + rb + r) * NS + gcol] = f2bu(acc[j][r] + bz);
    }
}

// ======== full decoder layer, 16 rows per block (512 blocks) ========
// SELF=0: query = LN1(tgt)+qemb, sample from value (vstride) at refp
// SELF=1: query = tgt+pos, sample at pixel ref (mostly OOB)
template<int SELF>
__global__ __launch_bounds__(256) void layer_kernel(
        float* __restrict__ tgt, const float* __restrict__ posq,
        const float* __restrict__ g1, const float* __restrict__ b1,
        const ushort* __restrict__ woffawL, const float* __restrict__ bOAL,
        const ushort* __restrict__ value, int vstride,
        const float* __restrict__ refp,
        const ushort* __restrict__ woutL, const float* __restrict__ out_bL,
        const float* __restrict__ g2, const float* __restrict__ b2,
        const ushort* __restrict__ wf1L, const float* __restrict__ f1_bL,
        const ushort* __restrict__ wf2L, const float* __restrict__ f2_bL) {
    __shared__ ushort Abuf[16 * 264];
    __shared__ float Slds[16 * 200];
    __shared__ float pred[2][4][16];
    const int t = threadIdx.x;
    const int m0 = blockIdx.x * 16;

    // ---- phase 0: stage query tile (LN1+qemb | +pos) ----
    {
        const int rg = t >> 4, lj = t & 15, c0 = lj * 16;
        int m = m0 + rg, q = m & (NQQ - 1);
        const float* src = tgt + (size_t)m * 256 + c0;
        float fv[16];
        #pragma unroll
        for (int j = 0; j < 4; j++) *(float4*)&fv[j * 4] = *(const float4*)(src + j * 4);
        if (!SELF) {
            float s = 0.0f;
            #pragma unroll
            for (int k = 0; k < 16; k++) s += fv[k];
            s += __shfl_xor(s, 1); s += __shfl_xor(s, 2);
            s += __shfl_xor(s, 4); s += __shfl_xor(s, 8);
            float mean = s * (1.0f / 256.0f);
            float s2 = 0.0f;
            #pragma unroll
            for (int k = 0; k < 16; k++) { float d = fv[k] - mean; s2 += d * d; }
            s2 += __shfl_xor(s2, 1); s2 += __shfl_xor(s2, 2);
            s2 += __shfl_xor(s2, 4); s2 += __shfl_xor(s2, 8);
            float rstd = rsqrtf(s2 * (1.0f / 256.0f) + 1e-5f);
            const float* ep = posq + (size_t)q * 512 + c0;   // qemb[:, :C]
            #pragma unroll
            for (int k = 0; k < 16; k++)
                fv[k] = (fv[k] - mean) * rstd * g1[c0 + k] + b1[c0 + k] + ep[k];
        } else {
            const float* ep = posq + (size_t)q * 256 + c0;
            #pragma unroll
            for (int k = 0; k < 16; k++) fv[k] += ep[k];
        }
        ushort tmp[16];
        #pragma unroll
        for (int k = 0; k < 16; k++) tmp[k] = f2bu(fv[k]);
        ushort* dst = Abuf + rg * 264 + c0;
        *(int4*)dst = *(const int4*)tmp;
        *(int4*)(dst + 8) = *(const int4*)(tmp + 8);
    }
    __syncthreads();

    const int l = t & 63, w = t >> 6;
    const int fr = l & 15, fk8 = (l >> 4) * 8, rb = (l >> 4) * 4;

    // ---- phase 1: offaw GEMM (192 cols, warp covers 48) ----
    {
        f4v oacc[3] = {};
        #pragma unroll
        for (int kk = 0; kk < 256; kk += 32) {
            s8v a = *(const s8v*)(Abuf + fr * 264 + kk + fk8);
            #pragma unroll
            for (int j = 0; j < 3; j++) {
                s8v b = *(const s8v*)(woffawL + (size_t)(w * 48 + j * 16 + fr) * 256 + kk + fk8);
                oacc[j] = __builtin_amdgcn_mfma_f32_16x16x32_bf16(a, b, oacc[j], 0, 0, 0);
            }
        }
        #pragma unroll
        for (int j = 0; j < 3; j++) {
            int gcol = w * 48 + j * 16 + fr;
            float bz = bOAL[gcol];
            #pragma unroll
            for (int r = 0; r < 4; r++)
                Slds[(rb + r) * 200 + gcol] = oacc[j][r] + bz;
        }
    }
    __syncthreads();

    // ---- phase 2: softmax + bilinear sampling -> Abuf (bf16 samp) ----
    {
        const int u = t >> 1, dh = t & 1;
        const int row = u >> 3, h = u & 7;
        int m = m0 + row, q = m & (NQQ - 1), bidx = m >> 12;
        float rxs, rys;
        if (SELF) { rxs = (float)(q & 63) * 64.0f + 32.0f; rys = (float)(q >> 6) * 64.0f + 32.0f; }
        else      { rxs = refp[q * 2] * 64.0f;             rys = refp[q * 2 + 1] * 64.0f; }
        const float* oa = Slds + row * 200;
        float lg[8];
        #pragma unroll
        for (int p = 0; p < 8; p++) lg[p] = oa[128 + h * 8 + p];
        float mx = lg[0];
        #pragma unroll
        for (int p = 1; p < 8; p++) mx = fmaxf(mx, lg[p]);
        float wg[8], wsum = 0.0f;
        #pragma unroll
        for (int p = 0; p < 8; p++) { wg[p] = __expf(lg[p] - mx); wsum += wg[p]; }
        float inv = 1.0f / wsum;
        const float* offp = oa + h * 16;
        const ushort* vb = value + (size_t)bidx * NQQ * vstride + h * 32 + dh * 16;
        float acc[16] = {};
        #pragma unroll
        for (int p = 0; p < 8; p++) {
            float px = rxs + offp[p * 2]     - 0.5f;
            float py = rys + offp[p * 2 + 1] - 0.5f;
            float x0f = floorf(px), y0f = floorf(py);
            float lx = px - x0f, ly = py - y0f;
            int x0 = (int)x0f, y0 = (int)y0f;
            float wgt = wg[p] * inv;
            float w00 = (1 - lx) * (1 - ly) * wgt, w10 = lx * (1 - ly) * wgt;
            float w01 = (1 - lx) * ly * wgt,       w11 = lx * ly * wgt;
            #pragma unroll
            for (int cn = 0; cn < 4; cn++) {
                int xi = x0 + (cn & 1), yi = y0 + (cn >> 1);
                float wc = (cn == 0) ? w00 : (cn == 1) ? w10 : (cn == 2) ? w01 : w11;
                if (xi >= 0 && xi < 64 && yi >= 0 && yi < 64) {
                    const ushort* cp = vb + (size_t)(yi * 64 + xi) * vstride;
                    uint4 u0 = *(const uint4*)cp;
                    uint4 u1 = *(const uint4*)(cp + 8);
                    uint ua[8] = {u0.x, u0.y, u0.z, u0.w, u1.x, u1.y, u1.z, u1.w};
                    #pragma unroll
                    for (int k = 0; k < 8; k++) {
                        uint lo = ua[k] << 16;
                        uint hi = ua[k] & 0xffff0000u;
                        acc[k * 2 + 0] += wc * *reinterpret_cast<float*>(&lo);
                        acc[k * 2 + 1] += wc * *reinterpret_cast<float*>(&hi);
                    }
                }
            }
        }
        ushort pk[16];
        #pragma unroll
        for (int k = 0; k < 16; k++) pk[k] = f2bu(acc[k]);
        ushort* dst = Abuf + row * 264 + h * 32 + dh * 16;
        *(int4*)dst = *(const int4*)pk;
        *(int4*)(dst + 8) = *(const int4*)(pk + 8);
    }
    __syncthreads();

    // ---- phase 3: out-proj + residual (v in regs) + LN2 stats ----
    float v[4][4];
    {
        f4v acc[4] = {};
        #pragma unroll
        for (int kk = 0; kk < 256; kk += 32) {
            s8v a = *(const s8v*)(Abuf + fr * 264 + kk + fk8);
            #pragma unroll
            for (int j = 0; j < 4; j++) {
                s8v b = *(const s8v*)(woutL + (size_t)(w * 64 + j * 16 + fr) * 256 + kk + fk8);
                acc[j] = __builtin_amdgcn_mfma_f32_16x16x32_bf16(a, b, acc[j], 0, 0, 0);
            }
        }
        float ls[4] = {}, lq[4] = {};
        #pragma unroll
        for (int j = 0; j < 4; j++) {
            int gcol = w * 64 + j * 16 + fr;
            float bz = out_bL[gcol];
            #pragma unroll
            for (int r = 0; r < 4; r++) {
                float tv = tgt[(size_t)(m0 + rb + r) * 256 + gcol] + acc[j][r] + bz;
                v[r][j] = tv;
                ls[r] += tv;
                lq[r] += tv * tv;
            }
        }
        #pragma unroll
        for (int o = 1; o < 16; o <<= 1)
            #pragma unroll
            for (int r = 0; r < 4; r++) {
                ls[r] += __shfl_xor(ls[r], o);
                lq[r] += __shfl_xor(lq[r], o);
            }
        if (fr == 0)
            #pragma unroll
            for (int r = 0; r < 4; r++) {
                pred[0][w][rb + r] = ls[r];
                pred[1][w][rb + r] = lq[r];
            }
    }
    __syncthreads();

    // ---- LN2 normalize -> Abuf ----
    #pragma unroll
    for (int r = 0; r < 4; r++) {
        int rloc = rb + r;
        float s = 0.0f, sq = 0.0f;
        #pragma unroll
        for (int ww = 0; ww < 4; ww++) { s += pred[0][ww][rloc]; sq += pred[1][ww][rloc]; }
        float mean = s * (1.0f / 256.0f);
        float var = sq * (1.0f / 256.0f) - mean * mean;
        float rstd = rsqrtf(var + 1e-5f);
        #pragma unroll
        for (int j = 0; j < 4; j++) {
            int gcol = w * 64 + j * 16 + fr;
            Abuf[rloc * 264 + gcol] = f2bu((v[r][j] - mean) * rstd * g2[gcol] + b2[gcol]);
        }
    }
    __syncthreads();

    // ---- phase 4: FFN1 + relu -> Abuf ----
    {
        f4v acc[4] = {};
        #pragma unroll
        for (int kk = 0; kk < 256; kk += 32) {
            s8v a = *(const s8v*)(Abuf + fr * 264 + kk + fk8);
            #pragma unroll
            for (int j = 0; j < 4; j++) {
                s8v b = *(const s8v*)(wf1L + (size_t)(w * 64 + j * 16 + fr) * 256 + kk + fk8);
                acc[j] = __builtin_amdgcn_mfma_f32_16x16x32_bf16(a, b, acc[j], 0, 0, 0);
            }
        }
        __syncthreads();
        #pragma unroll
        for (int j = 0; j < 4; j++) {
            int gcol = w * 64 + j * 16 + fr;
            float bz = f1_bL[gcol];
            #pragma unroll
            for (int r = 0; r < 4; r++)
                Abuf[(rb + r) * 264 + gcol] = f2bu(fmaxf(acc[j][r] + bz, 0.0f));
        }
    }
    __syncthreads();

    // ---- phase 5: FFN2 + relu + residual, final write ----
    {
        f4v acc[4] = {};
        #pragma unroll
        for (int kk = 0; kk < 256; kk += 32) {
            s8v a = *(const s8v*)(Abuf + fr * 264 + kk + fk8);
            #pragma unroll
            for (int j = 0; j < 4; j++) {
                s8v b = *(const s8v*)(wf2L + (size_t)(w * 64 + j * 16 + fr) * 256 + kk + fk8);
                acc[j] = __builtin_amdgcn_mfma_f32_16x16x32_bf16(a, b, acc[j], 0, 0, 0);
            }
        }
        #pragma unroll
        for (int j = 0; j < 4; j++) {
            int gcol = w * 64 + j * 16 + fr;
            float bz = f2_bL[gcol];
            #pragma unroll
            for (int r = 0; r < 4; r++)
                tgt[(size_t)(m0 + rb + r) * 256 + gcol] = v[r][j] + fmaxf(acc[j][r] + bz, 0.0f);
        }
    }
}

extern "C" void kernel_launch(void* const* d_in, const int* in_sizes, int n_in,
                              void* d_out, int out_size, void* d_ws, size_t ws_size,
                              hipStream_t stream) {
    const float* feat0 = (const float*)d_in[0];
    const float* feat1 = (const float*)d_in[1];
    const float* qemb  = (const float*)d_in[2];
    const float* ref_w = (const float*)d_in[3];
    const float* ref_b = (const float*)d_in[4];
    const float* fl    = (const float*)d_in[5];
    const float* ln1_g = (const float*)d_in[6];
    const float* ln1_b = (const float*)d_in[7];
    const float* off_w = (const float*)d_in[8];
    const float* off_b = (const float*)d_in[9];
    const float* aw_w  = (const float*)d_in[10];
    const float* aw_b  = (const float*)d_in[11];
    const float* val_w = (const float*)d_in[12];
    const float* val_b = (const float*)d_in[13];
    const float* out_w = (const float*)d_in[14];
    const float* out_b = (const float*)d_in[15];
    const float* ln2_g = (const float*)d_in[16];
    const float* ln2_b = (const float*)d_in[17];
    const float* f1_w  = (const float*)d_in[18];
    const float* f1_b  = (const float*)d_in[19];
    const float* f2_w  = (const float*)d_in[20];
    const float* f2_b  = (const float*)d_in[21];

    float* tgt = (float*)d_out;
    float* ws = (float*)d_ws;
    float* pos     = ws;                                     // 1,048,576 f32
    float* refp    = pos + 1048576;                          // 8,192 f32
    float* bOA     = refp + 8192;                            // 768 f32
    ushort* value01= (ushort*)(bOA + 768);                   // MT*512
    ushort* wval01 = value01 + (size_t)MT * 512;             // 131072
    ushort* wvalS  = wval01 + 131072;                        // 131072
    ushort* woffaw = wvalS + 131072;                         // 196608
    ushort* wout   = woffaw + 196608;                        // 262144
    ushort* wf1    = wout + 262144;                          // 262144
    ushort* wf2    = wf1 + 262144;                           // 262144
    ushort* fused_bf = wf2 + 262144;                         // MT*256

    setup_kernel<<<5940, 256, 0, stream>>>(qemb, ref_w, ref_b, feat0, feat1, fl,
                                           val_w, off_w, aw_w, out_w, f1_w, f2_w,
                                           off_b, aw_b,
                                           pos, refp, tgt,
                                           wval01, wvalS, woffaw, wout, wf1, wf2,
                                           bOA, fused_bf);

    // value projections for both cross layers: [MT,512] bf16
    pgemm<0><<<dim3(512, 2), 256, 0, stream>>>(fused_bf, nullptr, wval01, val_b, value01, 512);

    for (int i = 0; i < 2; i++) {       // cross layers
        layer_kernel<0><<<512, 256, 0, stream>>>(
            tgt, qemb, ln1_g + i * CC, ln1_b + i * CC,
            woffaw + (size_t)i * 49152, bOA + i * 192,
            value01 + i * 256, 512, refp,
            wout + (size_t)i * 65536, out_b + i * CC,
            ln2_g + i * CC, ln2_b + i * CC,
            wf1 + (size_t)i * 65536, f1_b + i * CC,
            wf2 + (size_t)i * 65536, f2_b + i * CC);
    }
    for (int i = 2; i < 4; i++) {       // self layers
        pgemm<1><<<dim3(512, 1), 256, 0, stream>>>(
            nullptr, tgt, wvalS + (size_t)(i - 2) * 65536, val_b + i * CC, value01, 256);
        layer_kernel<1><<<512, 256, 0, stream>>>(
            tgt, pos, nullptr, nullptr,
            woffaw + (size_t)i * 49152, bOA + i * 192,
            value01, 256, refp,
            wout + (size_t)i * 65536, out_b + i * CC,
            ln2_g + i * CC, ln2_b + i * CC,
            wf1 + (size_t)i * 65536, f1_b + i * CC,
            wf2 + (size_t)i * 65536, f2_b + i * CC);
    }
}

// Round 7
// 142.621 us; speedup vs baseline: 2.0097x; 1.5374x over previous
//
#include <hip/hip_runtime.h>
#include <hip/hip_bf16.h>
#include <math.h>

#define CC   256
#define NQQ  4096
#define MT   8192

typedef __attribute__((ext_vector_type(8))) short s8v;
typedef __attribute__((ext_vector_type(4))) float f4v;

static __device__ __forceinline__ ushort f2bu(float f) {
    __hip_bfloat16 h = __float2bfloat16(f);
    return *reinterpret_cast<ushort*>(&h);
}

// Fragment layout for weights: Wf[((ntile*8 + kc)*64 + lane)*8 + e]
//   lane l supplies B rows (n = ntile*16 + (l&15)), k = kc*32 + (l>>4)*8 + e
// => a wave's fragment load is 64 lanes x 16B contiguous (1KB), fully coalesced.

// ======== setup: pos/refpts/tgt-init + weight->fragment transpose + fuse ========
__global__ __launch_bounds__(256) void setup_kernel(
        const float* __restrict__ qemb, const float* __restrict__ rw,
        const float* __restrict__ rb,
        const float* __restrict__ feat0, const float* __restrict__ feat1,
        const float* __restrict__ fl,
        const float* __restrict__ val_w, const float* __restrict__ off_w,
        const float* __restrict__ aw_w,  const float* __restrict__ out_w,
        const float* __restrict__ f1_w,  const float* __restrict__ f2_w,
        const float* __restrict__ off_b, const float* __restrict__ aw_b,
        float* __restrict__ pos, float* __restrict__ refp, float* __restrict__ tgt,
        ushort* __restrict__ wval01, ushort* __restrict__ wvalS,
        ushort* __restrict__ woffaw, ushort* __restrict__ wout,
        ushort* __restrict__ wf1, ushort* __restrict__ wf2,
        float* __restrict__ bOA, ushort* __restrict__ fused) {
    __shared__ float tl[64][65];
    int bid = blockIdx.x;
    int t = threadIdx.x;
    if (bid < 2048) {                       // pos
        int idx = bid * 256 + t;
        int q = idx >> 7, pp = idx & 127;
        int p = pp >> 6, u = pp & 63;
        float coordbase = (p == 0) ? (float)((q >> 6) + 1) : (float)((q & 63) + 1);
        float coord = coordbase * (6.28318530717958647692f / (64.0f + 1e-6f));
        float v = coord * exp2f(-0.20762050593046016f * (float)u);
        *(float2*)(pos + (size_t)q * 256 + p * 128 + u * 2) = make_float2(__sinf(v), __cosf(v));
        return;
    }
    if (bid < 3072) {                       // refpts
        int row = (bid - 2048) * 4 + (t >> 6);
        int l = t & 63;
        float4 v = *(const float4*)(qemb + (size_t)row * 512 + l * 4);
        float a0 = v.x * rw[(l * 4 + 0) * 2] + v.y * rw[(l * 4 + 1) * 2]
                 + v.z * rw[(l * 4 + 2) * 2] + v.w * rw[(l * 4 + 3) * 2];
        float a1 = v.x * rw[(l * 4 + 0) * 2 + 1] + v.y * rw[(l * 4 + 1) * 2 + 1]
                 + v.z * rw[(l * 4 + 2) * 2 + 1] + v.w * rw[(l * 4 + 3) * 2 + 1];
        #pragma unroll
        for (int o = 32; o > 0; o >>= 1) { a0 += __shfl_xor(a0, o); a1 += __shfl_xor(a1, o); }
        if (l == 0) {
            refp[row * 2 + 0] = 1.0f / (1.0f + __expf(-(a0 + rb[0])));
            refp[row * 2 + 1] = 1.0f / (1.0f + __expf(-(a1 + rb[1])));
        }
        return;
    }
    if (bid < 5120) {                       // tgt init
        int idx = (bid - 3072) * 256 + t;
        int c4 = idx & 63;
        int q = (idx >> 6) & (NQQ - 1);
        *(float4*)(tgt + (size_t)idx * 4) = *(const float4*)(qemb + (size_t)q * 512 + 256 + c4 * 4);
        return;
    }
    if (bid < 5428) {                       // weight prep -> fragment layout
        int wb = bid - 5120;
        if (wb >= 304) {
            int layer = wb - 304;
            if (t < 192)
                bOA[layer * 192 + t] = (t < 128) ? off_b[layer * 128 + t]
                                                 : aw_b[layer * 64 + (t - 128)];
            return;
        }
        const float* src; ushort* dstF; int srcStride, ntb, kcb;
        if (wb < 32) {
            int nt = wb & 7, kt = wb >> 3;
            int layer = nt >> 2, nn = (nt & 3) * 64;
            src = val_w + (size_t)layer * 65536 + (size_t)kt * 64 * 256 + nn; srcStride = 256;
            dstF = wval01; ntb = nt * 4; kcb = kt * 2;
        } else if (wb < 64) {
            int b = wb - 32; int layer = b >> 4; int kt = (b >> 2) & 3; int nt = b & 3;
            src = val_w + (size_t)(2 + layer) * 65536 + (size_t)kt * 64 * 256 + nt * 64; srcStride = 256;
            dstF = wvalS + (size_t)layer * 65536; ntb = nt * 4; kcb = kt * 2;
        } else if (wb < 112) {
            int b = wb - 64; int layer = b / 12; int rem = b % 12; int kt = rem / 3; int nt = rem % 3;
            if (nt < 2) { src = off_w + (size_t)layer * 256 * 128 + (size_t)kt * 64 * 128 + nt * 64; srcStride = 128; }
            else        { src = aw_w  + (size_t)layer * 256 * 64  + (size_t)kt * 64 * 64;            srcStride = 64;  }
            dstF = woffaw + (size_t)layer * 49152; ntb = nt * 4; kcb = kt * 2;
        } else {
            int b = wb - 112; int fam = b >> 6; int bb = b & 63;
            int layer = bb >> 4; int kt = (bb >> 2) & 3; int nt = bb & 3;
            const float* s0 = (fam == 0) ? out_w : ((fam == 1) ? f1_w : f2_w);
            ushort* d0      = (fam == 0) ? wout  : ((fam == 1) ? wf1  : wf2);
            src = s0 + (size_t)layer * 65536 + (size_t)kt * 64 * 256 + nt * 64; srcStride = 256;
            dstF = d0 + (size_t)layer * 65536; ntb = nt * 4; kcb = kt * 2;
        }
        int r = t >> 6, c = t & 63;
        #pragma unroll
        for (int rr = 0; rr < 64; rr += 4)                 // tl[k_local][n_local]
            tl[rr + r][c] = src[(size_t)(rr + r) * srcStride + c];
        __syncthreads();
        int l = t >> 2;               // 0..63 (lane of fragment)
        int e0 = (t & 3) * 2;         // 0,2,4,6
        int frow = l & 15;            // n within 16-tile
        int fcol = (l >> 4) * 8;      // k offset within chunk
        #pragma unroll
        for (int s = 0; s < 8; s++) {
            int ntl = s & 3, kcl = s >> 2;
            int ntile = ntb + ntl, kc = kcb + kcl;
            ushort2 val;
            val.x = f2bu(tl[kcl * 32 + fcol + e0    ][ntl * 16 + frow]);
            val.y = f2bu(tl[kcl * 32 + fcol + e0 + 1][ntl * 16 + frow]);
            *(ushort2*)(dstF + (((size_t)ntile * 8 + kc) * 64 + l) * 8 + e0) = val;
        }
        return;
    }
    {                                       // fuse
        int fb = bid - 5428;
        int b = fb >> 8;
        int c0 = ((fb >> 6) & 3) * 64;
        int q0 = (fb & 63) * 64;
        int r = t >> 6, c = t & 63;
        #pragma unroll
        for (int rr = 0; rr < 64; rr += 4) {
            int ch = c0 + rr + r;
            float l0 = fl[ch], l1 = fl[CC + ch];
            float m = fmaxf(l0, l1);
            float e0 = __expf(l0 - m), e1 = __expf(l1 - m);
            float inv = 1.0f / (e0 + e1);
            size_t o = ((size_t)b * CC + ch) * NQQ + q0 + c;
            tl[rr + r][c] = (feat0[o] * e0 + feat1[o] * e1) * inv;
        }
        __syncthreads();
        #pragma unroll
        for (int rr = 0; rr < 64; rr += 4)
            fused[((size_t)(b * NQQ + q0 + rr + r)) * CC + c0 + c] = f2bu(tl[c][rr + r]);
    }
}

// ======== projection GEMM: 16-row tiles, 512 threads, fragment-B ========
// ASRC 0: bf16 A; 1: f32 A (cast). NTJ fragments per wave. out bf16 stride NS.
template<int ASRC, int NTJ>
__global__ __launch_bounds__(512) void pgemm(const ushort* __restrict__ Abf,
        const float* __restrict__ Af, const ushort* __restrict__ Wf,
        const float* __restrict__ bias, ushort* __restrict__ Cb, int NS) {
    __shared__ ushort Abuf[16 * 264];
    const int t = threadIdx.x;
    const int m0 = blockIdx.x * 16;
    const int cb0 = blockIdx.y * 256;
    const int ntb = blockIdx.y * 16;
    {
        const int rg = t >> 5, c0 = (t & 31) * 8;
        ushort* dst = Abuf + rg * 264 + c0;
        if (ASRC == 0) {
            *(int4*)dst = *(const int4*)(Abf + (size_t)(m0 + rg) * 256 + c0);
        } else {
            const float* src = Af + (size_t)(m0 + rg) * 256 + c0;
            ushort tmp[8];
            #pragma unroll
            for (int j = 0; j < 2; j++) {
                float4 v = *(const float4*)(src + j * 4);
                tmp[j * 4 + 0] = f2bu(v.x); tmp[j * 4 + 1] = f2bu(v.y);
                tmp[j * 4 + 2] = f2bu(v.z); tmp[j * 4 + 3] = f2bu(v.w);
            }
            *(int4*)dst = *(const int4*)tmp;
        }
    }
    __syncthreads();
    const int l = t & 63, w = t >> 6;
    const int fr = l & 15, fk8 = (l >> 4) * 8, rb = (l >> 4) * 4;
    f4v acc[NTJ] = {};
    #pragma unroll
    for (int kc = 0; kc < 8; kc++) {
        s8v a = *(const s8v*)(Abuf + fr * 264 + kc * 32 + fk8);
        #pragma unroll
        for (int j = 0; j < NTJ; j++) {
            int nt = ntb + j * 8 + w;
            s8v b = *(const s8v*)(Wf + (((size_t)nt * 8 + kc) * 64 + l) * 8);
            acc[j] = __builtin_amdgcn_mfma_f32_16x16x32_bf16(a, b, acc[j], 0, 0, 0);
        }
    }
    #pragma unroll
    for (int j = 0; j < NTJ; j++) {
        int gcol = cb0 + (j * 8 + w) * 16 + fr;
        float bz = bias[gcol];
        #pragma unroll
        for (int r = 0; r < 4; r++)
            Cb[(size_t)(m0 + rb + r) * NS + gcol] = f2bu(acc[j][r] + bz);
    }
}

// ======== full decoder layer: 16 rows/block, 512 threads (8 waves) ========
template<int SELF>
__global__ __launch_bounds__(512) void layer_kernel(
        float* __restrict__ tgt, const float* __restrict__ posq,
        const float* __restrict__ g1, const float* __restrict__ b1,
        const ushort* __restrict__ woffawL, const float* __restrict__ bOAL,
        const ushort* __restrict__ value, int vstride,
        const float* __restrict__ refp,
        const ushort* __restrict__ woutL, const float* __restrict__ out_bL,
        const float* __restrict__ g2, const float* __restrict__ b2,
        const ushort* __restrict__ wf1L, const float* __restrict__ f1_bL,
        const ushort* __restrict__ wf2L, const float* __restrict__ f2_bL) {
    __shared__ ushort Abuf[16 * 264];
    __shared__ float Slds[16 * 200];
    __shared__ float pred[2][8][16];
    const int t = threadIdx.x;
    const int m0 = blockIdx.x * 16;

    // ---- phase 0: stage query tile (LN1+qemb | +pos), 8 cols/thread ----
    {
        const int rg = t >> 5, c0 = (t & 31) * 8;
        int m = m0 + rg, q = m & (NQQ - 1);
        const float* src = tgt + (size_t)m * 256 + c0;
        float fv[8];
        *(float4*)&fv[0] = *(const float4*)src;
        *(float4*)&fv[4] = *(const float4*)(src + 4);
        if (!SELF) {
            float s = 0.0f;
            #pragma unroll
            for (int k = 0; k < 8; k++) s += fv[k];
            s += __shfl_xor(s, 1); s += __shfl_xor(s, 2); s += __shfl_xor(s, 4);
            s += __shfl_xor(s, 8); s += __shfl_xor(s, 16);
            float mean = s * (1.0f / 256.0f);
            float s2 = 0.0f;
            #pragma unroll
            for (int k = 0; k < 8; k++) { float d = fv[k] - mean; s2 += d * d; }
            s2 += __shfl_xor(s2, 1); s2 += __shfl_xor(s2, 2); s2 += __shfl_xor(s2, 4);
            s2 += __shfl_xor(s2, 8); s2 += __shfl_xor(s2, 16);
            float rstd = rsqrtf(s2 * (1.0f / 256.0f) + 1e-5f);
            const float* ep = posq + (size_t)q * 512 + c0;     // qemb[:, :C]
            #pragma unroll
            for (int k = 0; k < 8; k++)
                fv[k] = (fv[k] - mean) * rstd * g1[c0 + k] + b1[c0 + k] + ep[k];
        } else {
            const float* ep = posq + (size_t)q * 256 + c0;
            #pragma unroll
            for (int k = 0; k < 8; k++) fv[k] += ep[k];
        }
        ushort tmp[8];
        #pragma unroll
        for (int k = 0; k < 8; k++) tmp[k] = f2bu(fv[k]);
        *(int4*)(Abuf + rg * 264 + c0) = *(const int4*)tmp;
    }
    __syncthreads();

    const int l = t & 63, w = t >> 6;
    const int fr = l & 15, fk8 = (l >> 4) * 8, rb = (l >> 4) * 4;

    // ---- phase 1: offaw GEMM (12 n-tiles over 8 waves) ----
    {
        f4v oacc[2] = {};
        #pragma unroll
        for (int kc = 0; kc < 8; kc++) {
            s8v a = *(const s8v*)(Abuf + fr * 264 + kc * 32 + fk8);
            #pragma unroll
            for (int j = 0; j < 2; j++) {
                int nt = j * 8 + w;
                if (nt < 12) {
                    s8v b = *(const s8v*)(woffawL + (((size_t)nt * 8 + kc) * 64 + l) * 8);
                    oacc[j] = __builtin_amdgcn_mfma_f32_16x16x32_bf16(a, b, oacc[j], 0, 0, 0);
                }
            }
        }
        #pragma unroll
        for (int j = 0; j < 2; j++) {
            int nt = j * 8 + w;
            if (nt < 12) {
                int gcol = nt * 16 + fr;
                float bz = bOAL[gcol];
                #pragma unroll
                for (int r = 0; r < 4; r++)
                    Slds[(rb + r) * 200 + gcol] = oacc[j][r] + bz;
            }
        }
    }
    __syncthreads();

    // ---- phase 2: softmax + bilinear sampling -> Abuf (row, h, 8ch per thread) ----
    {
        const int row = t >> 5, h = (t >> 2) & 7, d8 = t & 3;
        int m = m0 + row, q = m & (NQQ - 1), bidx = m >> 12;
        float rxs, rys;
        if (SELF) { rxs = (float)(q & 63) * 64.0f + 32.0f; rys = (float)(q >> 6) * 64.0f + 32.0f; }
        else      { rxs = refp[q * 2] * 64.0f;             rys = refp[q * 2 + 1] * 64.0f; }
        const float* oa = Slds + row * 200;
        float lg[8];
        #pragma unroll
        for (int p = 0; p < 8; p++) lg[p] = oa[128 + h * 8 + p];
        float mx = lg[0];
        #pragma unroll
        for (int p = 1; p < 8; p++) mx = fmaxf(mx, lg[p]);
        float wg[8], wsum = 0.0f;
        #pragma unroll
        for (int p = 0; p < 8; p++) { wg[p] = __expf(lg[p] - mx); wsum += wg[p]; }
        float inv = 1.0f / wsum;
        const float* offp = oa + h * 16;
        const ushort* vb = value + (size_t)bidx * NQQ * vstride + h * 32 + d8 * 8;
        float acc[8] = {};
        #pragma unroll
        for (int p = 0; p < 8; p++) {
            float px = rxs + offp[p * 2]     - 0.5f;
            float py = rys + offp[p * 2 + 1] - 0.5f;
            float x0f = floorf(px), y0f = floorf(py);
            float lx = px - x0f, ly = py - y0f;
            int x0 = (int)x0f, y0 = (int)y0f;
            float wgt = wg[p] * inv;
            float w00 = (1 - lx) * (1 - ly) * wgt, w10 = lx * (1 - ly) * wgt;
            float w01 = (1 - lx) * ly * wgt,       w11 = lx * ly * wgt;
            #pragma unroll
            for (int cn = 0; cn < 4; cn++) {
                int xi = x0 + (cn & 1), yi = y0 + (cn >> 1);
                float wc = (cn == 0) ? w00 : (cn == 1) ? w10 : (cn == 2) ? w01 : w11;
                if (xi >= 0 && xi < 64 && yi >= 0 && yi < 64) {
                    uint4 uv = *(const uint4*)(vb + (size_t)(yi * 64 + xi) * vstride);
                    uint ua[4] = {uv.x, uv.y, uv.z, uv.w};
                    #pragma unroll
                    for (int k = 0; k < 4; k++) {
                        uint lo = ua[k] << 16;
                        uint hi = ua[k] & 0xffff0000u;
                        acc[k * 2 + 0] += wc * *reinterpret_cast<float*>(&lo);
                        acc[k * 2 + 1] += wc * *reinterpret_cast<float*>(&hi);
                    }
                }
            }
        }
        ushort pk[8];
        #pragma unroll
        for (int k = 0; k < 8; k++) pk[k] = f2bu(acc[k]);
        *(int4*)(Abuf + row * 264 + h * 32 + d8 * 8) = *(const int4*)pk;
    }
    __syncthreads();

    // ---- phase 3: out-proj + residual (v in regs) + LN2 stats ----
    float v[4][2];
    {
        f4v acc[2] = {};
        #pragma unroll
        for (int kc = 0; kc < 8; kc++) {
            s8v a = *(const s8v*)(Abuf + fr * 264 + kc * 32 + fk8);
            #pragma unroll
            for (int j = 0; j < 2; j++) {
                int nt = j * 8 + w;
                s8v b = *(const s8v*)(woutL + (((size_t)nt * 8 + kc) * 64 + l) * 8);
                acc[j] = __builtin_amdgcn_mfma_f32_16x16x32_bf16(a, b, acc[j], 0, 0, 0);
            }
        }
        float ls[4] = {}, lq[4] = {};
        #pragma unroll
        for (int j = 0; j < 2; j++) {
            int gcol = (j * 8 + w) * 16 + fr;
            float bz = out_bL[gcol];
            #pragma unroll
            for (int r = 0; r < 4; r++) {
                float tv = tgt[(size_t)(m0 + rb + r) * 256 + gcol] + acc[j][r] + bz;
                v[r][j] = tv;
                ls[r] += tv;
                lq[r] += tv * tv;
            }
        }
        #pragma unroll
        for (int o = 1; o < 16; o <<= 1)
            #pragma unroll
            for (int r = 0; r < 4; r++) {
                ls[r] += __shfl_xor(ls[r], o);
                lq[r] += __shfl_xor(lq[r], o);
            }
        if (fr == 0)
            #pragma unroll
            for (int r = 0; r < 4; r++) {
                pred[0][w][rb + r] = ls[r];
                pred[1][w][rb + r] = lq[r];
            }
    }
    __syncthreads();

    // ---- LN2 normalize -> Abuf ----
    #pragma unroll
    for (int r = 0; r < 4; r++) {
        int rloc = rb + r;
        float s = 0.0f, sq = 0.0f;
        #pragma unroll
        for (int ww = 0; ww < 8; ww++) { s += pred[0][ww][rloc]; sq += pred[1][ww][rloc]; }
        float mean = s * (1.0f / 256.0f);
        float var = sq * (1.0f / 256.0f) - mean * mean;
        float rstd = rsqrtf(var + 1e-5f);
        #pragma unroll
        for (int j = 0; j < 2; j++) {
            int gcol = (j * 8 + w) * 16 + fr;
            Abuf[rloc * 264 + gcol] = f2bu((v[r][j] - mean) * rstd * g2[gcol] + b2[gcol]);
        }
    }
    __syncthreads();

    // ---- phase 4: FFN1 + relu -> Abuf ----
    {
        f4v acc[2] = {};
        #pragma unroll
        for (int kc = 0; kc < 8; kc++) {
            s8v a = *(const s8v*)(Abuf + fr * 264 + kc * 32 + fk8);
            #pragma unroll
            for (int j = 0; j < 2; j++) {
                int nt = j * 8 + w;
                s8v b = *(const s8v*)(wf1L + (((size_t)nt * 8 + kc) * 64 + l) * 8);
                acc[j] = __builtin_amdgcn_mfma_f32_16x16x32_bf16(a, b, acc[j], 0, 0, 0);
            }
        }
        __syncthreads();
        #pragma unroll
        for (int j = 0; j < 2; j++) {
            int gcol = (j * 8 + w) * 16 + fr;
            float bz = f1_bL[gcol];
            #pragma unroll
            for (int r = 0; r < 4; r++)
                Abuf[(rb + r) * 264 + gcol] = f2bu(fmaxf(acc[j][r] + bz, 0.0f));
        }
    }
    __syncthreads();

    // ---- phase 5: FFN2 + relu + residual, final write ----
    {
        f4v acc[2] = {};
        #pragma unroll
        for (int kc = 0; kc < 8; kc++) {
            s8v a = *(const s8v*)(Abuf + fr * 264 + kc * 32 + fk8);
            #pragma unroll
            for (int j = 0; j < 2; j++) {
                int nt = j * 8 + w;
                s8v b = *(const s8v*)(wf2L + (((size_t)nt * 8 + kc) * 64 + l) * 8);
                acc[j] = __builtin_amdgcn_mfma_f32_16x16x32_bf16(a, b, acc[j], 0, 0, 0);
            }
        }
        #pragma unroll
        for (int j = 0; j < 2; j++) {
            int gcol = (j * 8 + w) * 16 + fr;
            float bz = f2_bL[gcol];
            #pragma unroll
            for (int r = 0; r < 4; r++)
                tgt[(size_t)(m0 + rb + r) * 256 + gcol] = v[r][j] + fmaxf(acc[j][r] + bz, 0.0f);
        }
    }
}

extern "C" void kernel_launch(void* const* d_in, const int* in_sizes, int n_in,
                              void* d_out, int out_size, void* d_ws, size_t ws_size,
                              hipStream_t stream) {
    const float* feat0 = (const float*)d_in[0];
    const float* feat1 = (const float*)d_in[1];
    const float* qemb  = (const float*)d_in[2];
    const float* ref_w = (const float*)d_in[3];
    const float* ref_b = (const float*)d_in[4];
    const float* fl    = (const float*)d_in[5];
    const float* ln1_g = (const float*)d_in[6];
    const float* ln1_b = (const float*)d_in[7];
    const float* off_w = (const float*)d_in[8];
    const float* off_b = (const float*)d_in[9];
    const float* aw_w  = (const float*)d_in[10];
    const float* aw_b  = (const float*)d_in[11];
    const float* val_w = (const float*)d_in[12];
    const float* val_b = (const float*)d_in[13];
    const float* out_w = (const float*)d_in[14];
    const float* out_b = (const float*)d_in[15];
    const float* ln2_g = (const float*)d_in[16];
    const float* ln2_b = (const float*)d_in[17];
    const float* f1_w  = (const float*)d_in[18];
    const float* f1_b  = (const float*)d_in[19];
    const float* f2_w  = (const float*)d_in[20];
    const float* f2_b  = (const float*)d_in[21];

    float* tgt = (float*)d_out;
    float* ws = (float*)d_ws;
    float* pos     = ws;                                     // 1,048,576 f32
    float* refp    = pos + 1048576;                          // 8,192 f32
    float* bOA     = refp + 8192;                            // 768 f32
    ushort* value01= (ushort*)(bOA + 768);                   // MT*512
    ushort* wval01 = value01 + (size_t)MT * 512;             // 131072
    ushort* wvalS  = wval01 + 131072;                        // 131072
    ushort* woffaw = wvalS + 131072;                         // 196608
    ushort* wout   = woffaw + 196608;                        // 262144
    ushort* wf1    = wout + 262144;                          // 262144
    ushort* wf2    = wf1 + 262144;                           // 262144
    ushort* fused_bf = wf2 + 262144;                         // MT*256

    setup_kernel<<<5940, 256, 0, stream>>>(qemb, ref_w, ref_b, feat0, feat1, fl,
                                           val_w, off_w, aw_w, out_w, f1_w, f2_w,
                                           off_b, aw_b,
                                           pos, refp, tgt,
                                           wval01, wvalS, woffaw, wout, wf1, wf2,
                                           bOA, fused_bf);

    // value projections for both cross layers: [MT,512] bf16
    pgemm<0, 2><<<dim3(512, 2), 512, 0, stream>>>(fused_bf, nullptr, wval01, val_b, value01, 512);

    for (int i = 0; i < 2; i++) {       // cross layers
        layer_kernel<0><<<512, 512, 0, stream>>>(
            tgt, qemb, ln1_g + i * CC, ln1_b + i * CC,
            woffaw + (size_t)i * 49152, bOA + i * 192,
            value01 + i * 256, 512, refp,
            wout + (size_t)i * 65536, out_b + i * CC,
            ln2_g + i * CC, ln2_b + i * CC,
            wf1 + (size_t)i * 65536, f1_b + i * CC,
            wf2 + (size_t)i * 65536, f2_b + i * CC);
    }
    for (int i = 2; i < 4; i++) {       // self layers
        pgemm<1, 2><<<dim3(512, 1), 512, 0, stream>>>(
            nullptr, tgt, wvalS + (size_t)(i - 2) * 65536, val_b + i * CC, value01, 256);
        layer_kernel<1><<<512, 512, 0, stream>>>(
            tgt, pos, nullptr, nullptr,
            woffaw + (size_t)i * 49152, bOA + i * 192,
            value01, 256, refp,
            wout + (size_t)i * 65536, out_b + i * CC,
            ln2_g + i * CC, ln2_b + i * CC,
            wf1 + (size_t)i * 65536, f1_b + i * CC,
            wf2 + (size_t)i * 65536, f2_b + i * CC);
    }
}